// Round 5
// baseline (283.512 us; speedup 1.0000x reference)
//
#include <hip/hip_runtime.h>
#include <hip/hip_bf16.h>

// ---------------------------------------------------------------------------
// CausalCrisisLoss on MI355X.  R9: 64x64 tiles + reg-prefetch; 6 -> 4 nodes.
//  * k_pre  = detect+prep+cls (A) | rowstats+u (B) | recon (C) |
//             sort (S: spins on A+B done) | transpose (T: spins on B done)
//             -- device-scope atomic-flag handshakes (G16 pattern)
//  * k_big  = role M [0,128): Chat^T Shat bf16 MFMA, K-split 4, reg-prefetch
//             role T [128,..): sorted-row 64x64 Gram tiles, reg-prefetch
//             double-buffer (global->reg early, reg->LDS late), register
//             MMD epilogue, <=4 atomics/wave
//  * k_fin  = blocks 0-15: hsic partials; block 16: spins, then finalize
// No float atomics anywhere: u64 fx2^32 / fx2^16 native global atomics.
// Bit-deterministic across replays.
// ---------------------------------------------------------------------------

typedef short bf16x8 __attribute__((ext_vector_type(8)));
typedef float f32x4 __attribute__((ext_vector_type(4)));
typedef unsigned long long u64;
typedef unsigned int u32;

static constexpr int D = 256;
static constexpr int H = 768;
static constexpr int NG = 16;
static constexpr float FX32 = 4294967296.f;
static constexpr float IFX32 = 2.3283064365386963e-10f;

__device__ inline void gAddFx(u64* p, float v) {
  long long q = (long long)llroundf(v * FX32);
  atomicAdd(p, (u64)q);                           // native global_atomic_add_x2
}
__device__ inline float fxToF(u64 v) { return (float)(long long)v * IFX32; }

__device__ inline void flagRelease(u64* f) {
  __threadfence();
  atomicAdd(f, 1ull);
}
__device__ inline void flagAcquire(u64* f, u64 n) {
  while (atomicAdd(f, 0ull) < n) __builtin_amdgcn_s_sleep(8);
  __threadfence();
}

__device__ inline float focal_n(const float* x, int n, int tgt,
                                float s_over_n, float oms) {
  float mx = x[0];
  for (int c = 1; c < n; ++c) mx = fmaxf(mx, x[c]);
  float se = 0.f, sx = 0.f;
  for (int c = 0; c < n; ++c) { se += __expf(x[c] - mx); sx += x[c]; }
  float logZ = mx + __logf(se);
  float ce = logZ - oms * x[tgt] - s_over_n * sx;
  float pt = __expf(x[tgt] - logZ);
  float om = 1.f - pt;
  return ce * om * om;
}

// ============================================================== k_pre (fused)
// role A [0,NA):          mode-detect + maskf/gid/counts + cls
// role B [NA,NA+NB):      per-row norms (8-row ILP), bf16 copy, sq, inv, u
// role C [NA+NB,+NC):     recon MSE
// role S [+NC,+NC+NA):    ballot-rank counting sort   (waits FLG0==NA, FLG1==NB)
// role T [+NC+NA,..):     transpose+normalize -> bnT  (waits FLG1==NB)
extern "C" __global__ __launch_bounds__(256) void k_pre(
    const void* __restrict__ mask, const int* __restrict__ y1,
    const int* __restrict__ dom,
    const float* __restrict__ l1, const float* __restrict__ l2,
    const float* __restrict__ l3, const int* __restrict__ y2,
    const int* __restrict__ y3,
    const float* __restrict__ vsv, const float* __restrict__ vst,
    const float* __restrict__ cv, const float* __restrict__ sv,
    const float* __restrict__ ct, const float* __restrict__ st,
    const float* __restrict__ ir, const float* __restrict__ io,
    const float* __restrict__ trc, const float* __restrict__ to,
    u64* SA, u64* GCU, u64* U64,
    int* gid, float* sq, float* inv, unsigned short* bf, u32* CNTB,
    int* perm, float* sqp, int* OFF, unsigned short* bnT, u64* FLG,
    int B, int N4, int NA, int NB) {
  __shared__ u32 sh3[3];
  __shared__ u32 cnt[17];
  __shared__ int redi[4];
  __shared__ float redf[4];
  __shared__ float redf5[5][4];
  __shared__ float ub[4][64][4];
  __shared__ float ld[64 * 65];              // transpose tile (16.6 KB)
  __shared__ u32 cbs[17], tots[17], wcnt[4][17];
  __shared__ u32 sbase[18];
  int bid = blockIdx.x;
  int t = threadIdx.x;
  int NC = 1024;

  if (bid < NA) {
    // ---------------- role A: detect + prep + cls ----------------
    if (t < 3) sh3[t] = 0;
    if (t < 17) cnt[t] = 0;
    __syncthreads();
    u32 a = 0, b2 = 0, cd = 0;
    if (t * 16 + 15 < B) {
      uint4 wv = ((const uint4*)mask)[t];
      u32 ws[4] = {wv.x, wv.y, wv.z, wv.w};
      #pragma unroll
      for (int j = 0; j < 4; ++j) {
        a |= ws[j] & 0xffu; b2 |= ws[j] & 0xff00u; cd |= ws[j] & 0xffff0000u;
      }
    }
    if (a) atomicOr(&sh3[0], 1u);
    if (b2) atomicOr(&sh3[1], 1u);
    if (cd) atomicOr(&sh3[2], 1u);
    __syncthreads();
    int mode;
    if ((sh3[1] | sh3[2]) == 0) mode = 0;          // int32 0/1
    else if (sh3[0] == 0 && sh3[1] == 0) mode = 1; // f32
    else mode = 2;                                 // u8
    int r = bid * 256 + t;
    int mi = 0;
    float s[5] = {0.f, 0.f, 0.f, 0.f, 0.f};
    if (r < B) {
      if (mode == 0)      mi = ((const int*)mask)[r] ? 1 : 0;
      else if (mode == 1) mi = (((const float*)mask)[r] != 0.f) ? 1 : 0;
      else                mi = ((const unsigned char*)mask)[r] ? 1 : 0;
      int g = -1;
      if (mi) { g = y1[r] * 4 + dom[r]; atomicAdd(&cnt[g], 1u); }
      else atomicAdd(&cnt[16], 1u);
      gid[r] = g;
      if (mi) {
        float x[6];
        for (int c = 0; c < 4; ++c) x[c] = l1[r * 4 + c];
        s[0] = focal_n(x, 4, y1[r], 0.1f / 4.f, 0.9f);
        for (int c = 0; c < 6; ++c) x[c] = l2[r * 6 + c];
        s[1] = focal_n(x, 6, y2[r], 0.1f / 6.f, 0.9f);
        for (int c = 0; c < 3; ++c) x[c] = l3[r * 3 + c];
        s[2] = focal_n(x, 3, y3[r], 0.1f / 3.f, 0.9f);
        int d = dom[r];
        for (int c = 0; c < 4; ++c) x[c] = vsv[r * 4 + c];
        {
          float mx = fmaxf(fmaxf(x[0], x[1]), fmaxf(x[2], x[3]));
          float se = __expf(x[0]-mx)+__expf(x[1]-mx)+__expf(x[2]-mx)+__expf(x[3]-mx);
          s[3] = mx + __logf(se) - x[d];
        }
        for (int c = 0; c < 4; ++c) x[c] = vst[r * 4 + c];
        {
          float mx = fmaxf(fmaxf(x[0], x[1]), fmaxf(x[2], x[3]));
          float se = __expf(x[0]-mx)+__expf(x[1]-mx)+__expf(x[2]-mx)+__expf(x[3]-mx);
          s[4] = mx + __logf(se) - x[d];
        }
      }
    }
    int v = mi;
    #pragma unroll
    for (int o = 32; o > 0; o >>= 1) {
      v += __shfl_down(v, o);
      #pragma unroll
      for (int k = 0; k < 5; ++k) s[k] += __shfl_down(s[k], o);
    }
    if ((t & 63) == 0) {
      redi[t >> 6] = v;
      #pragma unroll
      for (int k = 0; k < 5; ++k) redf5[k][t >> 6] = s[k];
    }
    __syncthreads();
    if (t == 0) {
      atomicAdd(&SA[5], (u64)(redi[0] + redi[1] + redi[2] + redi[3]));
      #pragma unroll
      for (int k = 0; k < 5; ++k)
        gAddFx(&SA[k], redf5[k][0] + redf5[k][1] + redf5[k][2] + redf5[k][3]);
    }
    if (t < NG && cnt[t]) atomicAdd(&GCU[t], (u64)cnt[t]);
    if (t < 17) CNTB[bid * 17 + t] = cnt[t];
    __syncthreads();
    if (t == 0) flagRelease(&FLG[0]);
  } else if (bid < NA + NB) {
    // ---------------- role B: rowstats + u (8-row ILP batch) ----------------
    int b = bid - NA;
    int perF = NB >> 2;                      // blocks per feature
    int f = b / perF;                        // 0..3  (cv, sv, ct, st)
    int rb = b - f * perF;                   // 32-row chunk index
    const float* p = (f == 0) ? cv : (f == 1) ? sv : (f == 2) ? ct : st;
    int w = t >> 6, L = t & 63;
    int rbase = rb * 32 + w * 8;
    float4 vv[8];
    #pragma unroll
    for (int i = 0; i < 8; ++i)
      vv[i] = ((const float4*)(p + (size_t)(rbase + i) * D))[L];
    float ss[8];
    #pragma unroll
    for (int i = 0; i < 8; ++i)
      ss[i] = vv[i].x * vv[i].x + vv[i].y * vv[i].y
            + vv[i].z * vv[i].z + vv[i].w * vv[i].w;
    #pragma unroll
    for (int o = 32; o > 0; o >>= 1) {
      #pragma unroll
      for (int i = 0; i < 8; ++i) ss[i] += __shfl_down(ss[i], o);
    }
    #pragma unroll
    for (int i = 0; i < 8; ++i) ss[i] = __shfl(ss[i], 0);
    float up0 = 0.f, up1 = 0.f, up2 = 0.f, up3 = 0.f;
    #pragma unroll
    for (int i = 0; i < 8; ++i) {
      int r = rbase + i;
      float iv = 1.f / fmaxf(sqrtf(ss[i]), 1e-12f);
      if ((f & 1) == 0) {
        int fi = f >> 1;
        alignas(8) __hip_bfloat16 hb[4];
        hb[0] = __float2bfloat16(vv[i].x); hb[1] = __float2bfloat16(vv[i].y);
        hb[2] = __float2bfloat16(vv[i].z); hb[3] = __float2bfloat16(vv[i].w);
        *(uint2*)(bf + ((size_t)fi * B + r) * D + L * 4) = *(uint2*)hb;
        if (L == 0) sq[fi * B + r] = ss[i];
      }
      if (L == 0) inv[f * B + r] = iv;
      up0 += vv[i].x * iv; up1 += vv[i].y * iv;
      up2 += vv[i].z * iv; up3 += vv[i].w * iv;
    }
    ub[w][L][0] = up0; ub[w][L][1] = up1; ub[w][L][2] = up2; ub[w][L][3] = up3;
    __syncthreads();
    if (t < 64) {
      u64* Uf = U64 + f * D + 4 * t;
      #pragma unroll
      for (int j = 0; j < 4; ++j) {
        float s4 = ub[0][t][j] + ub[1][t][j] + ub[2][t][j] + ub[3][t][j];
        gAddFx(Uf + j, s4);
      }
    }
    __syncthreads();
    if (t == 0) flagRelease(&FLG[1]);
  } else if (bid < NA + NB + NC) {
    // ---------------- role C: recon (static chunks, dual loads) ------------
    int cidx = bid - (NA + NB);
    int j = cidx >> 9;                       // 0/1: img / txt  (512 blocks ea)
    int cb = cidx & 511;
    const float4* A  = (const float4*)(j ? trc : ir);
    const float4* Bp = (const float4*)(j ? to : io);
    int CH = (N4 + 511) >> 9;                // per-block chunk (1536 @ B=4096)
    int base = cb * CH;
    int end = min(base + CH, N4);
    float acc = 0.f;
    int idx = base + t;
    for (; idx + 256 < end; idx += 512) {
      float4 a0 = A[idx],       b0 = Bp[idx];
      float4 a1 = A[idx + 256], b1 = Bp[idx + 256];
      float dx0 = a0.x-b0.x, dy0 = a0.y-b0.y, dz0 = a0.z-b0.z, dw0 = a0.w-b0.w;
      float dx1 = a1.x-b1.x, dy1 = a1.y-b1.y, dz1 = a1.z-b1.z, dw1 = a1.w-b1.w;
      acc += dx0*dx0 + dy0*dy0 + dz0*dz0 + dw0*dw0
           + dx1*dx1 + dy1*dy1 + dz1*dz1 + dw1*dw1;
    }
    if (idx < end) {
      float4 a = A[idx], b = Bp[idx];
      float dx = a.x-b.x, dy = a.y-b.y, dz = a.z-b.z, dw = a.w-b.w;
      acc += dx*dx + dy*dy + dz*dz + dw*dw;
    }
    #pragma unroll
    for (int o = 32; o > 0; o >>= 1) acc += __shfl_down(acc, o);
    if ((t & 63) == 0) redf[t >> 6] = acc;
    __syncthreads();
    if (t == 0) gAddFx(&SA[6 + j], redf[0] + redf[1] + redf[2] + redf[3]);
  } else if (bid < NA + NB + NC + NA) {
    // ---------------- role S: counting sort (waits on A, B) ----------------
    if (t == 0) {
      flagAcquire(&FLG[0], (u64)NA);
      flagAcquire(&FLG[1], (u64)NB);
    }
    __syncthreads();
    int b = bid - (NA + NB + NC);
    if (t < 68) ((u32*)wcnt)[t] = 0;
    if (t < 17) {
      u32 cb = 0, tot = 0;
      for (int b2 = 0; b2 < NA; ++b2) {
        u32 c = CNTB[b2 * 17 + t];
        cb += (b2 < b) ? c : 0u;
        tot += c;
      }
      cbs[t] = cb; tots[t] = tot;
    }
    int r = b * 256 + t;
    int g = 16;
    if (r < B) { int gg = gid[r]; g = (gg < 0) ? 16 : gg; }
    __syncthreads();
    if (t == 0) {
      u32 s = 0;
      for (int g2 = 0; g2 < 17; ++g2) { sbase[g2] = s; s += tots[g2]; }
      sbase[17] = s;
    }
    // 5-bit ballot same-group mask (all lanes participate)
    u64 msk = ~0ull;
    #pragma unroll
    for (int bit = 0; bit < 5; ++bit) {
      int bv = (g >> bit) & 1;
      u64 bl = __ballot(bv);
      msk &= bv ? bl : ~bl;
    }
    int lane = t & 63, w = t >> 6;
    int rwave = __popcll(msk & ((1ull << lane) - 1ull));
    if (rwave == 0) wcnt[w][g] = (u32)__popcll(msk);
    __syncthreads();
    if (r < B) {
      int rank = rwave;
      for (int w2 = 0; w2 < 4; ++w2) if (w2 < w) rank += (int)wcnt[w2][g];
      int pos = (int)(sbase[g] + cbs[g]) + rank;
      perm[pos] = r;
      sqp[pos] = sq[r];
      sqp[B + pos] = sq[B + r];
    }
    if (b == 0 && t < 18) OFF[t] = (int)sbase[t];
  } else {
    // ---------------- role T: transpose + normalize (waits on B) -----------
    if (t == 0) flagAcquire(&FLG[1], (u64)NB);
    __syncthreads();
    int TPF = (B >> 6) * 4;                  // tiles per feature
    int tb = bid - (NA + NB + NC + NA);
    int fm = tb / TPF, tile = tb - fm * TPF;
    int it = tile >> 2, at = tile & 3;
    const float* src = (fm == 0) ? cv : (fm == 1) ? sv : (fm == 2) ? ct : st;
    const float* ivf = inv + (size_t)fm * B;
    int i0 = it * 64, a0 = at * 64;
    for (int e = t; e < 1024; e += 256) {
      int i = e >> 4, c4 = e & 15;
      float4 v = ((const float4*)(src + (size_t)(i0 + i) * D))[at * 16 + c4];
      float ivv = ivf[i0 + i];
      ld[i * 65 + c4 * 4 + 0] = v.x * ivv;
      ld[i * 65 + c4 * 4 + 1] = v.y * ivv;
      ld[i * 65 + c4 * 4 + 2] = v.z * ivv;
      ld[i * 65 + c4 * 4 + 3] = v.w * ivv;
    }
    __syncthreads();
    unsigned short* dst = bnT + (size_t)fm * D * B;
    for (int e = t; e < 512; e += 256) {
      int a = e >> 3, ic = e & 7;
      alignas(16) unsigned short h[8];
      #pragma unroll
      for (int j = 0; j < 8; ++j) {
        __hip_bfloat16 hb = __float2bfloat16(ld[(ic * 8 + j) * 65 + a]);
        h[j] = *(unsigned short*)&hb;
      }
      *(uint4*)(dst + (size_t)(a0 + a) * B + i0 + ic * 8) = *(uint4*)h;
    }
  }
}

// ============================================================== k_big (fused)
// role M [0,128): M = Chat^T Shat bf16 MFMA, 64x64 tiles, K-split 4, f32 out
// role T [128, 128+2*2080): sorted-row 64x64 Gram tiles, reg-prefetch dbuf,
//   register MMD epilogue
extern "C" __global__ __launch_bounds__(256) void k_big(
    const unsigned short* __restrict__ bf, const float* __restrict__ sqp,
    const int* __restrict__ perm, const int* __restrict__ OFF,
    const unsigned short* __restrict__ bnT, float* __restrict__ Mf32,
    u64* GSP, int B) {
  __shared__ __align__(16) char smem[17536];
  unsigned short* Ab = (unsigned short*)smem;               // 8 KB
  unsigned short* Bb = (unsigned short*)(smem + 8192);      // 8 KB
  int bid = blockIdx.x;
  int tid = threadIdx.x;
  int w = tid >> 6, L = tid & 63, m = L & 15, q = L >> 4;
  int r0 = tid >> 3, ck = tid & 7;
  int swz = (ck ^ (r0 & 7)) * 8;
  int ar = w * 16 + m;

  if (bid < 128) {
    // ---------------- role M: bf16 MFMA GEMM (64x64 out, K-split 4) --------
    int ks = bid & 3, bb = (bid >> 2) & 3, ab = (bid >> 4) & 3, p = (bid >> 6) & 1;
    const unsigned short* Abase = bnT + (size_t)(2 * p) * D * B;
    const unsigned short* Bbase = bnT + (size_t)(2 * p + 1) * D * B;
    size_t kof = (size_t)ks * (B >> 2) + ck * 8;
    const uint4* gA0 = (const uint4*)(Abase + (size_t)(ab * 64 + r0) * B + kof);
    const uint4* gA1 = (const uint4*)(Abase + (size_t)(ab * 64 + r0 + 32) * B + kof);
    const uint4* gB0 = (const uint4*)(Bbase + (size_t)(bb * 64 + r0) * B + kof);
    const uint4* gB1 = (const uint4*)(Bbase + (size_t)(bb * 64 + r0 + 32) * B + kof);
    uint4* dA0 = (uint4*)&Ab[r0 * 64 + swz];
    uint4* dA1 = (uint4*)&Ab[(r0 + 32) * 64 + swz];
    uint4* dB0 = (uint4*)&Bb[r0 * 64 + swz];
    uint4* dB1 = (uint4*)&Bb[(r0 + 32) * 64 + swz];
    f32x4 acc[4] = {{0.f,0.f,0.f,0.f},{0.f,0.f,0.f,0.f},
                    {0.f,0.f,0.f,0.f},{0.f,0.f,0.f,0.f}};
    int nh = B >> 8;                         // rounds of K=64 per quarter
    uint4 rA0 = gA0[0], rA1 = gA1[0], rB0 = gB0[0], rB1 = gB1[0];
    for (int hq = 0; hq < nh; ++hq) {
      *dA0 = rA0; *dA1 = rA1; *dB0 = rB0; *dB1 = rB1;
      __syncthreads();
      if (hq < nh - 1) {
        rA0 = gA0[(hq + 1) * 8]; rA1 = gA1[(hq + 1) * 8];
        rB0 = gB0[(hq + 1) * 8]; rB1 = gB1[(hq + 1) * 8];
      }
      #pragma unroll
      for (int kk = 0; kk < 2; ++kk) {
        bf16x8 aF = *(const bf16x8*)&Ab[ar * 64 + (((kk * 4 + q) ^ (ar & 7)) * 8)];
        #pragma unroll
        for (int c = 0; c < 4; ++c) {
          int br = c * 16 + m;
          bf16x8 bF = *(const bf16x8*)&Bb[br * 64 + (((kk * 4 + q) ^ (br & 7)) * 8)];
          acc[c] = __builtin_amdgcn_mfma_f32_16x16x32_bf16(aF, bF, acc[c], 0, 0, 0);
        }
      }
      if (hq < nh - 1) __syncthreads();
    }
    // plain f32 stores: this block exclusively owns its output tile
    float* Mo = Mf32 + (size_t)(ks * 2 + p) * D * D;
    int ri0 = w * 16 + q * 4;
    #pragma unroll
    for (int c = 0; c < 4; ++c) {
      #pragma unroll
      for (int v = 0; v < 4; ++v)
        Mo[(size_t)(ab * 64 + ri0 + v) * D + bb * 64 + c * 16 + m] = acc[c][v];
    }
    return;
  }

  // ---------------- role T: 64x64 mmd tile (sorted rows) ----------------
  float* sA = (float*)(smem + 16384);                       // 256 B
  float* sB = (float*)(smem + 16640);                       // 256 B
  int*   pA = (int*)(smem + 16896);                         // 256 B
  int*   pB = (int*)(smem + 17152);                         // 256 B
  int*   offs = (int*)(smem + 17408);                       // 72 B

  int idx2 = bid - 128;
  int feat = idx2 & 1;
  int tlin = idx2 >> 1;
  int NT = B / 64;
  float tf = (float)tlin;
  int ti = (int)((2.f * NT + 1.f -
                  sqrtf((2.f * NT + 1.f) * (2.f * NT + 1.f) - 8.f * tf)) * 0.5f);
  while (ti > 0 && (ti * NT - (ti * (ti - 1)) / 2) > tlin) --ti;
  while (((ti + 1) * NT - ((ti + 1) * ti) / 2) <= tlin) ++ti;
  int tj = ti + (tlin - (ti * NT - (ti * (ti - 1)) / 2));
  int i0 = ti * 64, j0 = tj * 64;
  bool diag = (ti == tj);
  const unsigned short* fb = bf + (size_t)feat * B * D;
  const float* sqf = sqp + (size_t)feat * B;

  if (tid < 64) { pA[tid] = perm[i0 + tid]; sA[tid] = sqf[i0 + tid]; }
  else if (tid < 128) { int r = tid - 64; pB[r] = perm[j0 + r]; sB[r] = sqf[j0 + r]; }
  else if (tid < 146) offs[tid - 128] = OFF[tid - 128];
  __syncthreads();

  // block-uniform group / boundary analysis
  int gr0 = 0, nbr = 0, gc0 = 0, ncb = 0;
  #pragma unroll
  for (int g = 1; g <= 17; ++g) {
    int o = offs[g];
    gr0 += (o <= i0) ? 1 : 0;
    nbr += (o > i0 && o < i0 + 64) ? 1 : 0;
    gc0 += (o <= j0) ? 1 : 0;
    ncb += (o > j0 && o < j0 + 64) ? 1 : 0;
  }
  if (gr0 == 16 || gc0 == 16) return;        // tile entirely invalid-masked
  int gr1 = gr0 + nbr;
  int gc1 = gc0 + ncb;
  int s_r = nbr ? offs[gr1] : i0 + 64;
  int s_c = ncb ? offs[gc1] : j0 + 64;

  // hoisted staging pointers (fixed row/chunk per thread; per-round imm offset)
  const uint4* gA0 = (const uint4*)(fb + (size_t)pA[r0] * D + ck * 8);
  const uint4* gA1 = (const uint4*)(fb + (size_t)pA[r0 + 32] * D + ck * 8);
  uint4* dA0 = (uint4*)&Ab[r0 * 64 + swz];
  uint4* dA1 = (uint4*)&Ab[(r0 + 32) * 64 + swz];
  const uint4* gB0 = gA0; const uint4* gB1 = gA1;
  uint4* dB0 = (uint4*)&Bb[r0 * 64 + swz];
  uint4* dB1 = (uint4*)&Bb[(r0 + 32) * 64 + swz];
  if (!diag) {
    gB0 = (const uint4*)(fb + (size_t)pB[r0] * D + ck * 8);
    gB1 = (const uint4*)(fb + (size_t)pB[r0 + 32] * D + ck * 8);
  }
  const unsigned short* Bp = diag ? Ab : Bb;

  f32x4 acc[4] = {{0.f,0.f,0.f,0.f},{0.f,0.f,0.f,0.f},
                  {0.f,0.f,0.f,0.f},{0.f,0.f,0.f,0.f}};

  // reg-prefetch double buffer: global->reg issued under MFMA phase
  uint4 rA0 = gA0[0], rA1 = gA1[0], rB0, rB1;
  if (!diag) { rB0 = gB0[0]; rB1 = gB1[0]; }
  for (int hq = 0; hq < 4; ++hq) {           // K rounds of 64
    *dA0 = rA0; *dA1 = rA1;
    if (!diag) { *dB0 = rB0; *dB1 = rB1; }
    __syncthreads();
    if (hq < 3) {
      rA0 = gA0[(hq + 1) * 8]; rA1 = gA1[(hq + 1) * 8];
      if (!diag) { rB0 = gB0[(hq + 1) * 8]; rB1 = gB1[(hq + 1) * 8]; }
    }
    #pragma unroll
    for (int kk = 0; kk < 2; ++kk) {
      bf16x8 aF = *(const bf16x8*)&Ab[ar * 64 + (((kk * 4 + q) ^ (ar & 7)) * 8)];
      #pragma unroll
      for (int c = 0; c < 4; ++c) {
        int br = c * 16 + m;
        bf16x8 bF = *(const bf16x8*)&Bp[br * 64 + (((kk * 4 + q) ^ (br & 7)) * 8)];
        acc[c] = __builtin_amdgcn_mfma_f32_16x16x32_bf16(aF, bF, acc[c], 0, 0, 0);
      }
    }
    if (hq < 3) __syncthreads();
  }

  // epilogue: C/D layout col=lane&15, row=(lane>>4)*4+reg (m89/m91).
  int ri0 = w * 16 + q * 4;
  u64* gsp = GSP + ((size_t)(tlin & 63) * 2 + feat) * NG * NG;

  if (nbr <= 1 && ncb <= 1) {
    // fast path: <=2 groups per side -> 4 register accumulators
    float siv[4]; bool rhiv[4];
    #pragma unroll
    for (int v = 0; v < 4; ++v) {
      siv[v] = sA[ri0 + v];
      rhiv[v] = (i0 + ri0 + v) >= s_r;
    }
    float a00 = 0.f, a01 = 0.f, a10 = 0.f, a11 = 0.f;
    #pragma unroll
    for (int c = 0; c < 4; ++c) {
      int rj = c * 16 + m;
      float sb = sB[rj];
      float lo = 0.f, hi = 0.f;
      #pragma unroll
      for (int v = 0; v < 4; ++v) {
        float d = fmaxf(siv[v] + sb - 2.f * acc[c][v], 0.f);
        float K = __expf(-0.01f * d) + __expf(-0.1f * d) + __expf(-d)
                + __expf(-10.f * d) + __expf(-100.f * d);
        if (diag) {
          int ri = ri0 + v;
          K = (ri > rj) ? 0.f : (ri == rj) ? 5.f : K;
        }
        float kh = rhiv[v] ? K : 0.f;
        hi += kh; lo += K - kh;
      }
      bool chi = (j0 + rj) >= s_c;
      float loH = chi ? lo : 0.f;
      float hiH = chi ? hi : 0.f;
      a00 += lo - loH; a01 += loH;
      a10 += hi - hiH; a11 += hiH;
    }
    #pragma unroll
    for (int o = 32; o > 0; o >>= 1) {
      a00 += __shfl_down(a00, o); a01 += __shfl_down(a01, o);
      a10 += __shfl_down(a10, o); a11 += __shfl_down(a11, o);
    }
    if (L == 0) {
      if (a00 != 0.f)
        atomicAdd(&gsp[gr0 * NG + gc0], (u64)(long long)llroundf(a00 * 65536.f));
      if (a01 != 0.f && gc1 < 16)
        atomicAdd(&gsp[gr0 * NG + gc1], (u64)(long long)llroundf(a01 * 65536.f));
      if (a10 != 0.f && gr1 < 16)
        atomicAdd(&gsp[gr1 * NG + gc0], (u64)(long long)llroundf(a10 * 65536.f));
      if (a11 != 0.f && gr1 < 16 && gc1 < 16)
        atomicAdd(&gsp[gr1 * NG + gc1], (u64)(long long)llroundf(a11 * 65536.f));
    }
  } else {
    // rare fallback: per-element group scan + global fx atomics (correctness)
    int giv[4]; float siv[4];
    #pragma unroll
    for (int v = 0; v < 4; ++v) {
      int idx = i0 + ri0 + v;
      int g = 0;
      #pragma unroll
      for (int k = 1; k <= 16; ++k) g += (offs[k] <= idx) ? 1 : 0;
      giv[v] = g;
      siv[v] = sA[ri0 + v];
    }
    #pragma unroll
    for (int c = 0; c < 4; ++c) {
      int rj = c * 16 + m;
      int jdx = j0 + rj;
      int gj = 0;
      #pragma unroll
      for (int k = 1; k <= 16; ++k) gj += (offs[k] <= jdx) ? 1 : 0;
      float sb = sB[rj];
      #pragma unroll
      for (int v = 0; v < 4; ++v) {
        int ri = ri0 + v;
        if (giv[v] < 16 && gj < 16 && !(diag && ri > rj)) {
          float K;
          if (diag && ri == rj) K = 5.f;
          else {
            float d = fmaxf(siv[v] + sb - 2.f * acc[c][v], 0.f);
            K = __expf(-0.01f * d) + __expf(-0.1f * d) + __expf(-d)
              + __expf(-10.f * d) + __expf(-100.f * d);
          }
          u32 kf = (u32)(K * 65536.f + 0.5f);
          atomicAdd(&gsp[giv[v] * NG + gj], (u64)kf);
        }
      }
    }
  }
}

// ============================================================== k_fin
// blocks 0-15: hsic partials tr(KL), u^T M v  -> SA (atomic fx)
// block 16:    waits FLG2==16, then finalize
extern "C" __global__ __launch_bounds__(256) void k_fin(
    const u64* __restrict__ U64, const float* __restrict__ Mf32,
    u64* SA, const u64* __restrict__ GCU, const u64* __restrict__ GSP,
    float* out, u64* FLG, int B) {
  __shared__ float red[8];
  __shared__ float ush[32], vsh[D];
  __shared__ float gssh[2 * NG * NG];
  int bid = blockIdx.x;
  int t = threadIdx.x;

  if (bid < 16) {
    // ---------------- hsic partials ----------------
    int p = bid >> 3;
    int k0 = (bid & 7) * 32;
    vsh[t] = fxToF(U64[(2 * p + 1) * D + t]);
    if (t < 32) ush[t] = fxToF(U64[(2 * p) * D + k0 + t]);
    __syncthreads();
    const float* M0 = Mf32 + (size_t)(0 * 2 + p) * D * D;
    const float* M1 = Mf32 + (size_t)(1 * 2 + p) * D * D;
    const float* M2 = Mf32 + (size_t)(2 * 2 + p) * D * D;
    const float* M3 = Mf32 + (size_t)(3 * 2 + p) * D * D;
    float trkl = 0.f, cr = 0.f;
    #pragma unroll 4
    for (int k = 0; k < 32; ++k) {
      size_t off = (size_t)(k0 + k) * D + t;
      float mv = M0[off] + M1[off] + M2[off] + M3[off];
      trkl += mv * mv;
      cr += ush[k] * mv;
    }
    cr *= vsh[t];
    #pragma unroll
    for (int o = 32; o > 0; o >>= 1) { trkl += __shfl_down(trkl, o); cr += __shfl_down(cr, o); }
    if ((t & 63) == 0) { red[t >> 6] = trkl; red[4 + (t >> 6)] = cr; }
    __syncthreads();
    if (t == 0) gAddFx(&SA[10 + p], red[0] + red[1] + red[2] + red[3]);
    if (t == 64) gAddFx(&SA[12 + p], red[4] + red[5] + red[6] + red[7]);
    __syncthreads();
    if (t == 0) flagRelease(&FLG[2]);
    return;
  }

  // ---------------- finalize (block 16) ----------------
  if (t == 0) flagAcquire(&FLG[2], 16ull);
  __syncthreads();
  for (int e = t; e < 2 * NG * NG; e += 256) {
    u64 ssum = 0;
    int f = e >> 8, idx = e & 255;
    for (int cpy = 0; cpy < 64; ++cpy)
      ssum += GSP[((size_t)cpy * 2 + f) * NG * NG + idx];
    gssh[e] = (float)((double)ssum * (1.0 / 65536.0));
  }
  __syncthreads();

  float n = (float)B;
  float hs[2];
  for (int p = 0; p < 2; ++p) {
    float ut = fxToF(U64[(2 * p) * D + t]);
    float vt = fxToF(U64[(2 * p + 1) * D + t]);
    float uu = ut * ut, vv = vt * vt;
    #pragma unroll
    for (int o = 32; o > 0; o >>= 1) { uu += __shfl_down(uu, o); vv += __shfl_down(vv, o); }
    __syncthreads();
    if ((t & 63) == 0) { red[t >> 6] = uu; red[4 + (t >> 6)] = vv; }
    __syncthreads();
    float uus = red[0] + red[1] + red[2] + red[3];
    float vvs = red[4] + red[5] + red[6] + red[7];
    float trkl = (float)((double)(long long)SA[10 + p] * (double)IFX32);
    float cr   = (float)((double)(long long)SA[12 + p] * (double)IFX32);
    hs[p] = (trkl - (2.f / n) * cr + uus * vvs / (n * n))
          / ((n - 1.f) * (n - 1.f));
    __syncthreads();
  }
  if (t == 0) {
    float msum = fmaxf((float)SA[5], 1.f);
    float f1 = fxToF(SA[0]) / msum;
    float f2 = fxToF(SA[1]) / msum;
    float f3 = fxToF(SA[2]) / msum;
    float cesv = fxToF(SA[3]) / msum;
    float cest = fxToF(SA[4]) / msum;
    float mmd[2];
    for (int f = 0; f < 2; ++f) {
      float loss = 0.f, cntv = 0.f;
      for (int lab = 0; lab < 4; ++lab)
        for (int d1 = 0; d1 < 4; ++d1)
          for (int d2 = d1 + 1; d2 < 4; ++d2) {
            int a = lab * 4 + d1, b = lab * 4 + d2;
            float n1 = (float)GCU[a], n2 = (float)GCU[b];
            if (n1 > 1.f && n2 > 1.f) {
              float g11 = 2.f * gssh[f * 256 + a * NG + a] - 5.f * n1;
              float g22 = 2.f * gssh[f * 256 + b * NG + b] - 5.f * n2;
              float g12 = gssh[f * 256 + a * NG + b];
              loss += g11 / (fmaxf(n1, 1.f) * fmaxf(n1, 1.f))
                    + g22 / (fmaxf(n2, 1.f) * fmaxf(n2, 1.f))
                    - 2.f * g12 / fmaxf(n1 * n2, 1.f);
              cntv += 1.f;
            }
          }
      mmd[f] = loss / fmaxf(cntv, 1.f);
    }
    double rs = ((double)(long long)SA[6] + (double)(long long)SA[7])
              * (double)IFX32;
    float recon = (float)(rs / ((double)B * (double)H));
    float total = 0.4f * f1 + 0.3f * f2 + 0.3f * f3
                + 0.1f * (cesv + cest + mmd[0] + mmd[1])
                + 0.1f * (hs[0] + hs[1])
                + recon;
    out[0] = total;
  }
}

// ---------------------------------------------------------------------------
extern "C" void kernel_launch(void* const* d_in, const int* in_sizes, int n_in,
                              void* d_out, int out_size, void* d_ws, size_t ws_size,
                              hipStream_t stream) {
  const float* l1  = (const float*)d_in[0];
  const int*   y1  = (const int*)d_in[1];
  const float* l2  = (const float*)d_in[2];
  const int*   y2  = (const int*)d_in[3];
  const float* l3  = (const float*)d_in[4];
  const int*   y3  = (const int*)d_in[5];
  const float* cv  = (const float*)d_in[6];
  const float* sv  = (const float*)d_in[7];
  const float* ct  = (const float*)d_in[8];
  const float* st  = (const float*)d_in[9];
  const float* vsv = (const float*)d_in[10];
  const float* vst = (const float*)d_in[11];
  const int*   dom = (const int*)d_in[12];
  const void*  mask= d_in[13];
  const float* ir  = (const float*)d_in[14];
  const float* io  = (const float*)d_in[15];
  const float* trc = (const float*)d_in[16];
  const float* to  = (const float*)d_in[17];
  int B = in_sizes[1];                        // 4096

  // workspace: u64 accumulators (zeroed) then scratch
  u64* SA  = (u64*)d_ws;                      // 32 slots
  u64* GCU = SA + 32;                         // 16
  u64* U64 = GCU + 16;                        // 4*256
  u64* GSP = U64 + 4 * D;                     // 64*2*256
  u64* FLG = GSP + 64 * 2 * NG * NG;          // 4 flags
  u64* zend = FLG + 4;
  size_t zeroBytes = (size_t)((char*)zend - (char*)d_ws);     // ~270 KB
  unsigned short* bf  = (unsigned short*)zend;                // 2*B*D bf16
  unsigned short* bnT = bf + 2 * (size_t)B * D;               // 4*D*B bf16
  float* Mf32 = (float*)(bnT + 4 * (size_t)D * B);            // 8*D*D f32
  int*   gid = (int*)(Mf32 + 8 * (size_t)D * D);              // B
  float* sq  = (float*)(gid + B);             // 2*B
  float* inv = sq + 2 * B;                    // 4*B
  int*   perm = (int*)(inv + 4 * B);          // B
  float* sqp  = (float*)(perm + B);           // 2*B (permuted sq)
  int*   OFF  = (int*)(sqp + 2 * B);          // 18 group offsets
  u32*   CNTB = (u32*)(OFF + 18);             // NA*17 per-block counts

  int NA = B / 256;                           // 16   prep+cls blocks
  int NB = B / 8;                             // 512  rowstats blocks (32 rows)
  int NC = 1024;                              // recon blocks (512 per half)
  int NTR = B / 4;                            // transpose blocks (1024)
  int N4 = B * H / 4;

  hipMemsetAsync(d_ws, 0, zeroBytes, stream);
  k_pre<<<NA + NB + NC + NA + NTR, 256, 0, stream>>>(
      mask, y1, dom, l1, l2, l3, y2, y3, vsv, vst,
      cv, sv, ct, st, ir, io, trc, to,
      SA, GCU, U64, gid, sq, inv, bf, CNTB,
      perm, sqp, OFF, bnT, FLG, B, N4, NA, NB);
  int NT = B / 64;
  int nmmd = 2 * (NT * (NT + 1) / 2);         // 4160
  k_big<<<128 + nmmd, 256, 0, stream>>>(bf, sqp, perm, OFF, bnT, Mf32, GSP, B);
  k_fin<<<17, 256, 0, stream>>>(U64, Mf32, SA, GCU, GSP, (float*)d_out, FLG, B);
}

// Round 6
// 210.181 us; speedup vs baseline: 1.3489x; 1.3489x over previous
//
#include <hip/hip_runtime.h>
#include <hip/hip_bf16.h>

// ---------------------------------------------------------------------------
// CausalCrisisLoss on MI355X.  R10: R7 baseline + k_big-local pipelining.
//  * k_pre  = detect+prep+cls (A) | rowstats+u (B: 8-row ILP) | recon (C)
//  * k_mid  = [0,NA): ballot-rank counting sort | [NA,..): transpose+normalize
//  * k_big  = role M [0,128): Chat^T Shat bf16 MFMA, K-split 4, reg-prefetch
//             role T [128,..): sorted-row 64x64 Gram tiles, reg-prefetch
//             double-buffer, register MMD epilogue, <=4 atomics/wave
//  * k_hsic = sums 4 M parts; k_final unchanged.
// No float atomics anywhere: u64 fx2^32 / fx2^16 native global atomics.
// Bit-deterministic across replays.
// ---------------------------------------------------------------------------

typedef short bf16x8 __attribute__((ext_vector_type(8)));
typedef float f32x4 __attribute__((ext_vector_type(4)));
typedef unsigned long long u64;
typedef unsigned int u32;

static constexpr int D = 256;
static constexpr int H = 768;
static constexpr int NG = 16;
static constexpr float FX32 = 4294967296.f;
static constexpr float IFX32 = 2.3283064365386963e-10f;

__device__ inline void gAddFx(u64* p, float v) {
  long long q = (long long)llroundf(v * FX32);
  atomicAdd(p, (u64)q);                           // native global_atomic_add_x2
}
__device__ inline float fxToF(u64 v) { return (float)(long long)v * IFX32; }

__device__ inline float focal_n(const float* x, int n, int tgt,
                                float s_over_n, float oms) {
  float mx = x[0];
  for (int c = 1; c < n; ++c) mx = fmaxf(mx, x[c]);
  float se = 0.f, sx = 0.f;
  for (int c = 0; c < n; ++c) { se += __expf(x[c] - mx); sx += x[c]; }
  float logZ = mx + __logf(se);
  float ce = logZ - oms * x[tgt] - s_over_n * sx;
  float pt = __expf(x[tgt] - logZ);
  float om = 1.f - pt;
  return ce * om * om;
}

// ============================================================== k_pre (fused)
// role A [0,NA):        mode-detect + maskf/gid/counts + cls (interleaved red)
// role B [NA,NA+NB):    per-row norms (8-row ILP batch), bf16 copy, sq, inv,
//                       u-partials (LDS cross-wave reduce)
// role C [NA+NB,+NC):   recon MSE, static chunks, dual-unrolled loads
extern "C" __global__ __launch_bounds__(256) void k_pre(
    const void* __restrict__ mask, const int* __restrict__ y1,
    const int* __restrict__ dom,
    const float* __restrict__ l1, const float* __restrict__ l2,
    const float* __restrict__ l3, const int* __restrict__ y2,
    const int* __restrict__ y3,
    const float* __restrict__ vsv, const float* __restrict__ vst,
    const float* __restrict__ cv, const float* __restrict__ sv,
    const float* __restrict__ ct, const float* __restrict__ st,
    const float* __restrict__ ir, const float* __restrict__ io,
    const float* __restrict__ trc, const float* __restrict__ to,
    u64* SA, u64* GCU, u64* U64,
    int* gid, float* sq, float* inv, unsigned short* bf, u32* CNTB,
    int B, int N4, int NA, int NB) {
  __shared__ u32 sh3[3];
  __shared__ u32 cnt[17];
  __shared__ int redi[4];
  __shared__ float redf[4];
  __shared__ float redf5[5][4];
  __shared__ float ub[4][64][4];
  int bid = blockIdx.x;
  int t = threadIdx.x;

  if (bid < NA) {
    // ---------------- role A: detect + prep + cls ----------------
    if (t < 3) sh3[t] = 0;
    if (t < 17) cnt[t] = 0;
    __syncthreads();
    u32 a = 0, b2 = 0, cd = 0;
    if (t * 16 + 15 < B) {
      uint4 wv = ((const uint4*)mask)[t];
      u32 ws[4] = {wv.x, wv.y, wv.z, wv.w};
      #pragma unroll
      for (int j = 0; j < 4; ++j) {
        a |= ws[j] & 0xffu; b2 |= ws[j] & 0xff00u; cd |= ws[j] & 0xffff0000u;
      }
    }
    if (a) atomicOr(&sh3[0], 1u);
    if (b2) atomicOr(&sh3[1], 1u);
    if (cd) atomicOr(&sh3[2], 1u);
    __syncthreads();
    int mode;
    if ((sh3[1] | sh3[2]) == 0) mode = 0;          // int32 0/1
    else if (sh3[0] == 0 && sh3[1] == 0) mode = 1; // f32
    else mode = 2;                                 // u8
    int r = bid * 256 + t;
    int mi = 0;
    float s[5] = {0.f, 0.f, 0.f, 0.f, 0.f};
    if (r < B) {
      if (mode == 0)      mi = ((const int*)mask)[r] ? 1 : 0;
      else if (mode == 1) mi = (((const float*)mask)[r] != 0.f) ? 1 : 0;
      else                mi = ((const unsigned char*)mask)[r] ? 1 : 0;
      int g = -1;
      if (mi) { g = y1[r] * 4 + dom[r]; atomicAdd(&cnt[g], 1u); }
      else atomicAdd(&cnt[16], 1u);
      gid[r] = g;
      if (mi) {
        float x[6];
        for (int c = 0; c < 4; ++c) x[c] = l1[r * 4 + c];
        s[0] = focal_n(x, 4, y1[r], 0.1f / 4.f, 0.9f);
        for (int c = 0; c < 6; ++c) x[c] = l2[r * 6 + c];
        s[1] = focal_n(x, 6, y2[r], 0.1f / 6.f, 0.9f);
        for (int c = 0; c < 3; ++c) x[c] = l3[r * 3 + c];
        s[2] = focal_n(x, 3, y3[r], 0.1f / 3.f, 0.9f);
        int d = dom[r];
        for (int c = 0; c < 4; ++c) x[c] = vsv[r * 4 + c];
        {
          float mx = fmaxf(fmaxf(x[0], x[1]), fmaxf(x[2], x[3]));
          float se = __expf(x[0]-mx)+__expf(x[1]-mx)+__expf(x[2]-mx)+__expf(x[3]-mx);
          s[3] = mx + __logf(se) - x[d];
        }
        for (int c = 0; c < 4; ++c) x[c] = vst[r * 4 + c];
        {
          float mx = fmaxf(fmaxf(x[0], x[1]), fmaxf(x[2], x[3]));
          float se = __expf(x[0]-mx)+__expf(x[1]-mx)+__expf(x[2]-mx)+__expf(x[3]-mx);
          s[4] = mx + __logf(se) - x[d];
        }
      }
    }
    int v = mi;
    #pragma unroll
    for (int o = 32; o > 0; o >>= 1) {
      v += __shfl_down(v, o);
      #pragma unroll
      for (int k = 0; k < 5; ++k) s[k] += __shfl_down(s[k], o);
    }
    if ((t & 63) == 0) {
      redi[t >> 6] = v;
      #pragma unroll
      for (int k = 0; k < 5; ++k) redf5[k][t >> 6] = s[k];
    }
    __syncthreads();
    if (t == 0) {
      atomicAdd(&SA[5], (u64)(redi[0] + redi[1] + redi[2] + redi[3]));
      #pragma unroll
      for (int k = 0; k < 5; ++k)
        gAddFx(&SA[k], redf5[k][0] + redf5[k][1] + redf5[k][2] + redf5[k][3]);
    }
    if (t < NG && cnt[t]) atomicAdd(&GCU[t], (u64)cnt[t]);
    if (t < 17) CNTB[bid * 17 + t] = cnt[t];
  } else if (bid < NA + NB) {
    // ---------------- role B: rowstats + u (8-row ILP batch) ----------------
    int b = bid - NA;
    int perF = NB >> 2;                      // blocks per feature
    int f = b / perF;                        // 0..3  (cv, sv, ct, st)
    int rb = b - f * perF;                   // 32-row chunk index
    const float* p = (f == 0) ? cv : (f == 1) ? sv : (f == 2) ? ct : st;
    int w = t >> 6, L = t & 63;
    int rbase = rb * 32 + w * 8;
    float4 vv[8];
    #pragma unroll
    for (int i = 0; i < 8; ++i)
      vv[i] = ((const float4*)(p + (size_t)(rbase + i) * D))[L];
    float ss[8];
    #pragma unroll
    for (int i = 0; i < 8; ++i)
      ss[i] = vv[i].x * vv[i].x + vv[i].y * vv[i].y
            + vv[i].z * vv[i].z + vv[i].w * vv[i].w;
    #pragma unroll
    for (int o = 32; o > 0; o >>= 1) {
      #pragma unroll
      for (int i = 0; i < 8; ++i) ss[i] += __shfl_down(ss[i], o);
    }
    #pragma unroll
    for (int i = 0; i < 8; ++i) ss[i] = __shfl(ss[i], 0);
    float up0 = 0.f, up1 = 0.f, up2 = 0.f, up3 = 0.f;
    #pragma unroll
    for (int i = 0; i < 8; ++i) {
      int r = rbase + i;
      float iv = 1.f / fmaxf(sqrtf(ss[i]), 1e-12f);
      if ((f & 1) == 0) {
        int fi = f >> 1;
        alignas(8) __hip_bfloat16 hb[4];
        hb[0] = __float2bfloat16(vv[i].x); hb[1] = __float2bfloat16(vv[i].y);
        hb[2] = __float2bfloat16(vv[i].z); hb[3] = __float2bfloat16(vv[i].w);
        *(uint2*)(bf + ((size_t)fi * B + r) * D + L * 4) = *(uint2*)hb;
        if (L == 0) sq[fi * B + r] = ss[i];
      }
      if (L == 0) inv[f * B + r] = iv;
      up0 += vv[i].x * iv; up1 += vv[i].y * iv;
      up2 += vv[i].z * iv; up3 += vv[i].w * iv;
    }
    ub[w][L][0] = up0; ub[w][L][1] = up1; ub[w][L][2] = up2; ub[w][L][3] = up3;
    __syncthreads();
    if (t < 64) {
      u64* Uf = U64 + f * D + 4 * t;
      #pragma unroll
      for (int j = 0; j < 4; ++j) {
        float s4 = ub[0][t][j] + ub[1][t][j] + ub[2][t][j] + ub[3][t][j];
        gAddFx(Uf + j, s4);
      }
    }
  } else {
    // ---------------- role C: recon (static chunks, dual loads) ----------------
    int cidx = bid - (NA + NB);
    int j = cidx >> 9;                       // 0/1: img / txt  (512 blocks ea)
    int cb = cidx & 511;
    const float4* A  = (const float4*)(j ? trc : ir);
    const float4* Bp = (const float4*)(j ? to : io);
    int CH = (N4 + 511) >> 9;                // per-block chunk (1536 @ B=4096)
    int base = cb * CH;
    int end = min(base + CH, N4);
    float acc = 0.f;
    int idx = base + t;
    for (; idx + 256 < end; idx += 512) {
      float4 a0 = A[idx],       b0 = Bp[idx];
      float4 a1 = A[idx + 256], b1 = Bp[idx + 256];
      float dx0 = a0.x-b0.x, dy0 = a0.y-b0.y, dz0 = a0.z-b0.z, dw0 = a0.w-b0.w;
      float dx1 = a1.x-b1.x, dy1 = a1.y-b1.y, dz1 = a1.z-b1.z, dw1 = a1.w-b1.w;
      acc += dx0*dx0 + dy0*dy0 + dz0*dz0 + dw0*dw0
           + dx1*dx1 + dy1*dy1 + dz1*dz1 + dw1*dw1;
    }
    if (idx < end) {
      float4 a = A[idx], b = Bp[idx];
      float dx = a.x-b.x, dy = a.y-b.y, dz = a.z-b.z, dw = a.w-b.w;
      acc += dx*dx + dy*dy + dz*dz + dw*dw;
    }
    #pragma unroll
    for (int o = 32; o > 0; o >>= 1) acc += __shfl_down(acc, o);
    if ((t & 63) == 0) redf[t >> 6] = acc;
    __syncthreads();
    if (t == 0) gAddFx(&SA[6 + j], redf[0] + redf[1] + redf[2] + redf[3]);
  }
}

// ============================================================== k_mid
// [0,NA):   deterministic stable counting sort by gid via wave ballots
// [NA,..):  transpose + normalize features -> bnT[4][256][B] bf16
extern "C" __global__ __launch_bounds__(256) void k_mid(
    const u32* __restrict__ CNTB, const int* __restrict__ gid,
    const float* __restrict__ sq,
    const float* __restrict__ cv, const float* __restrict__ sv,
    const float* __restrict__ ct, const float* __restrict__ st,
    const float* __restrict__ inv,
    int* __restrict__ perm, float* __restrict__ sqp, int* __restrict__ OFF,
    unsigned short* __restrict__ bnT, int B, int NA) {
  __shared__ float ld[64 * 65];              // transpose tile (16.6 KB)
  __shared__ u32 cbs[17], tots[17], wcnt[4][17];
  __shared__ u32 base[18];
  int b = blockIdx.x, t = threadIdx.x;

  if (b < NA) {
    // ---------------- sort ----------------
    if (t < 68) ((u32*)wcnt)[t] = 0;
    if (t < 17) {
      u32 cb = 0, tot = 0;
      for (int b2 = 0; b2 < NA; ++b2) {
        u32 c = CNTB[b2 * 17 + t];
        cb += (b2 < b) ? c : 0u;
        tot += c;
      }
      cbs[t] = cb; tots[t] = tot;
    }
    int r = b * 256 + t;
    int g = 16;
    if (r < B) { int gg = gid[r]; g = (gg < 0) ? 16 : gg; }
    __syncthreads();
    if (t == 0) {
      u32 s = 0;
      for (int g2 = 0; g2 < 17; ++g2) { base[g2] = s; s += tots[g2]; }
      base[17] = s;
    }
    // 5-bit ballot same-group mask (all lanes participate)
    u64 msk = ~0ull;
    #pragma unroll
    for (int bit = 0; bit < 5; ++bit) {
      int bv = (g >> bit) & 1;
      u64 bl = __ballot(bv);
      msk &= bv ? bl : ~bl;
    }
    int lane = t & 63, w = t >> 6;
    int rwave = __popcll(msk & ((1ull << lane) - 1ull));
    if (rwave == 0) wcnt[w][g] = (u32)__popcll(msk);
    __syncthreads();
    if (r < B) {
      int rank = rwave;
      for (int w2 = 0; w2 < 4; ++w2) if (w2 < w) rank += (int)wcnt[w2][g];
      int pos = (int)(base[g] + cbs[g]) + rank;
      perm[pos] = r;
      sqp[pos] = sq[r];
      sqp[B + pos] = sq[B + r];
    }
    if (b == 0 && t < 18) OFF[t] = (int)base[t];
  } else {
    // ---------------- transpose + normalize ----------------
    int TPF = (B >> 6) * 4;                  // tiles per feature
    int tb = b - NA;
    int fm = tb / TPF, tile = tb - fm * TPF;
    int it = tile >> 2, at = tile & 3;
    const float* src = (fm == 0) ? cv : (fm == 1) ? sv : (fm == 2) ? ct : st;
    const float* ivf = inv + (size_t)fm * B;
    int i0 = it * 64, a0 = at * 64;
    for (int e = t; e < 1024; e += 256) {
      int i = e >> 4, c4 = e & 15;
      float4 v = ((const float4*)(src + (size_t)(i0 + i) * D))[at * 16 + c4];
      float ivv = ivf[i0 + i];
      ld[i * 65 + c4 * 4 + 0] = v.x * ivv;
      ld[i * 65 + c4 * 4 + 1] = v.y * ivv;
      ld[i * 65 + c4 * 4 + 2] = v.z * ivv;
      ld[i * 65 + c4 * 4 + 3] = v.w * ivv;
    }
    __syncthreads();
    unsigned short* dst = bnT + (size_t)fm * D * B;
    for (int e = t; e < 512; e += 256) {
      int a = e >> 3, ic = e & 7;
      alignas(16) unsigned short h[8];
      #pragma unroll
      for (int j = 0; j < 8; ++j) {
        __hip_bfloat16 hb = __float2bfloat16(ld[(ic * 8 + j) * 65 + a]);
        h[j] = *(unsigned short*)&hb;
      }
      *(uint4*)(dst + (size_t)(a0 + a) * B + i0 + ic * 8) = *(uint4*)h;
    }
  }
}

// ============================================================== k_big (fused)
// role M [0,128): M = Chat^T Shat bf16 MFMA, 64x64 tiles, K-split 4,
//   reg-prefetch, f32 out
// role T [128, 128+2*2080): sorted-row 64x64 Gram tiles, reg-prefetch dbuf,
//   register MMD epilogue
extern "C" __global__ __launch_bounds__(256) void k_big(
    const unsigned short* __restrict__ bf, const float* __restrict__ sqp,
    const int* __restrict__ perm, const int* __restrict__ OFF,
    const unsigned short* __restrict__ bnT, float* __restrict__ Mf32,
    u64* GSP, int B) {
  __shared__ __align__(16) char smem[17536];
  unsigned short* Ab = (unsigned short*)smem;               // 8 KB
  unsigned short* Bb = (unsigned short*)(smem + 8192);      // 8 KB
  int bid = blockIdx.x;
  int tid = threadIdx.x;
  int w = tid >> 6, L = tid & 63, m = L & 15, q = L >> 4;
  int r0 = tid >> 3, ck = tid & 7;
  int swz = (ck ^ (r0 & 7)) * 8;
  int ar = w * 16 + m;

  if (bid < 128) {
    // ---------------- role M: bf16 MFMA GEMM (64x64 out, K-split 4) --------
    int ks = bid & 3, bb = (bid >> 2) & 3, ab = (bid >> 4) & 3, p = (bid >> 6) & 1;
    const unsigned short* Abase = bnT + (size_t)(2 * p) * D * B;
    const unsigned short* Bbase = bnT + (size_t)(2 * p + 1) * D * B;
    size_t kof = (size_t)ks * (B >> 2) + ck * 8;
    const uint4* gA0 = (const uint4*)(Abase + (size_t)(ab * 64 + r0) * B + kof);
    const uint4* gA1 = (const uint4*)(Abase + (size_t)(ab * 64 + r0 + 32) * B + kof);
    const uint4* gB0 = (const uint4*)(Bbase + (size_t)(bb * 64 + r0) * B + kof);
    const uint4* gB1 = (const uint4*)(Bbase + (size_t)(bb * 64 + r0 + 32) * B + kof);
    uint4* dA0 = (uint4*)&Ab[r0 * 64 + swz];
    uint4* dA1 = (uint4*)&Ab[(r0 + 32) * 64 + swz];
    uint4* dB0 = (uint4*)&Bb[r0 * 64 + swz];
    uint4* dB1 = (uint4*)&Bb[(r0 + 32) * 64 + swz];
    f32x4 acc[4] = {{0.f,0.f,0.f,0.f},{0.f,0.f,0.f,0.f},
                    {0.f,0.f,0.f,0.f},{0.f,0.f,0.f,0.f}};
    int nh = B >> 8;                         // rounds of K=64 per quarter (16)
    uint4 rA0 = gA0[0], rA1 = gA1[0], rB0 = gB0[0], rB1 = gB1[0];
    for (int hq = 0; hq < nh; ++hq) {
      *dA0 = rA0; *dA1 = rA1; *dB0 = rB0; *dB1 = rB1;
      __syncthreads();
      if (hq < nh - 1) {
        rA0 = gA0[(hq + 1) * 8]; rA1 = gA1[(hq + 1) * 8];
        rB0 = gB0[(hq + 1) * 8]; rB1 = gB1[(hq + 1) * 8];
      }
      #pragma unroll
      for (int kk = 0; kk < 2; ++kk) {
        bf16x8 aF = *(const bf16x8*)&Ab[ar * 64 + (((kk * 4 + q) ^ (ar & 7)) * 8)];
        #pragma unroll
        for (int c = 0; c < 4; ++c) {
          int br = c * 16 + m;
          bf16x8 bF = *(const bf16x8*)&Bb[br * 64 + (((kk * 4 + q) ^ (br & 7)) * 8)];
          acc[c] = __builtin_amdgcn_mfma_f32_16x16x32_bf16(aF, bF, acc[c], 0, 0, 0);
        }
      }
      if (hq < nh - 1) __syncthreads();
    }
    // plain f32 stores: this block exclusively owns its output tile
    float* Mo = Mf32 + (size_t)(ks * 2 + p) * D * D;
    int ri0 = w * 16 + q * 4;
    #pragma unroll
    for (int c = 0; c < 4; ++c) {
      #pragma unroll
      for (int v = 0; v < 4; ++v)
        Mo[(size_t)(ab * 64 + ri0 + v) * D + bb * 64 + c * 16 + m] = acc[c][v];
    }
    return;
  }

  // ---------------- role T: 64x64 mmd tile (sorted rows) ----------------
  float* sA = (float*)(smem + 16384);                       // 256 B
  float* sB = (float*)(smem + 16640);                       // 256 B
  int*   pA = (int*)(smem + 16896);                         // 256 B
  int*   pB = (int*)(smem + 17152);                         // 256 B
  int*   offs = (int*)(smem + 17408);                       // 72 B

  int idx2 = bid - 128;
  int feat = idx2 & 1;
  int tlin = idx2 >> 1;
  int NT = B / 64;
  float tf = (float)tlin;
  int ti = (int)((2.f * NT + 1.f -
                  sqrtf((2.f * NT + 1.f) * (2.f * NT + 1.f) - 8.f * tf)) * 0.5f);
  while (ti > 0 && (ti * NT - (ti * (ti - 1)) / 2) > tlin) --ti;
  while (((ti + 1) * NT - ((ti + 1) * ti) / 2) <= tlin) ++ti;
  int tj = ti + (tlin - (ti * NT - (ti * (ti - 1)) / 2));
  int i0 = ti * 64, j0 = tj * 64;
  bool diag = (ti == tj);
  const unsigned short* fb = bf + (size_t)feat * B * D;
  const float* sqf = sqp + (size_t)feat * B;

  if (tid < 64) { pA[tid] = perm[i0 + tid]; sA[tid] = sqf[i0 + tid]; }
  else if (tid < 128) { int r = tid - 64; pB[r] = perm[j0 + r]; sB[r] = sqf[j0 + r]; }
  else if (tid < 146) offs[tid - 128] = OFF[tid - 128];
  __syncthreads();

  // block-uniform group / boundary analysis
  int gr0 = 0, nbr = 0, gc0 = 0, ncb = 0;
  #pragma unroll
  for (int g = 1; g <= 17; ++g) {
    int o = offs[g];
    gr0 += (o <= i0) ? 1 : 0;
    nbr += (o > i0 && o < i0 + 64) ? 1 : 0;
    gc0 += (o <= j0) ? 1 : 0;
    ncb += (o > j0 && o < j0 + 64) ? 1 : 0;
  }
  if (gr0 == 16 || gc0 == 16) return;        // tile entirely invalid-masked
  int gr1 = gr0 + nbr;
  int gc1 = gc0 + ncb;
  int s_r = nbr ? offs[gr1] : i0 + 64;
  int s_c = ncb ? offs[gc1] : j0 + 64;

  // hoisted staging pointers (fixed row/chunk per thread; per-round imm offset)
  const uint4* gA0 = (const uint4*)(fb + (size_t)pA[r0] * D + ck * 8);
  const uint4* gA1 = (const uint4*)(fb + (size_t)pA[r0 + 32] * D + ck * 8);
  uint4* dA0 = (uint4*)&Ab[r0 * 64 + swz];
  uint4* dA1 = (uint4*)&Ab[(r0 + 32) * 64 + swz];
  const uint4* gB0 = gA0; const uint4* gB1 = gA1;
  uint4* dB0 = (uint4*)&Bb[r0 * 64 + swz];
  uint4* dB1 = (uint4*)&Bb[(r0 + 32) * 64 + swz];
  if (!diag) {
    gB0 = (const uint4*)(fb + (size_t)pB[r0] * D + ck * 8);
    gB1 = (const uint4*)(fb + (size_t)pB[r0 + 32] * D + ck * 8);
  }
  const unsigned short* Bp = diag ? Ab : Bb;

  f32x4 acc[4] = {{0.f,0.f,0.f,0.f},{0.f,0.f,0.f,0.f},
                  {0.f,0.f,0.f,0.f},{0.f,0.f,0.f,0.f}};

  // reg-prefetch double buffer: next round's global loads issued under MFMA
  uint4 rA0 = gA0[0], rA1 = gA1[0], rB0, rB1;
  if (!diag) { rB0 = gB0[0]; rB1 = gB1[0]; }
  for (int hq = 0; hq < 4; ++hq) {           // K rounds of 64
    *dA0 = rA0; *dA1 = rA1;
    if (!diag) { *dB0 = rB0; *dB1 = rB1; }
    __syncthreads();
    if (hq < 3) {
      rA0 = gA0[(hq + 1) * 8]; rA1 = gA1[(hq + 1) * 8];
      if (!diag) { rB0 = gB0[(hq + 1) * 8]; rB1 = gB1[(hq + 1) * 8]; }
    }
    #pragma unroll
    for (int kk = 0; kk < 2; ++kk) {
      bf16x8 aF = *(const bf16x8*)&Ab[ar * 64 + (((kk * 4 + q) ^ (ar & 7)) * 8)];
      #pragma unroll
      for (int c = 0; c < 4; ++c) {
        int br = c * 16 + m;
        bf16x8 bF = *(const bf16x8*)&Bp[br * 64 + (((kk * 4 + q) ^ (br & 7)) * 8)];
        acc[c] = __builtin_amdgcn_mfma_f32_16x16x32_bf16(aF, bF, acc[c], 0, 0, 0);
      }
    }
    if (hq < 3) __syncthreads();
  }

  // epilogue: C/D layout col=lane&15, row=(lane>>4)*4+reg (m89/m91).
  int ri0 = w * 16 + q * 4;
  u64* gsp = GSP + ((size_t)(tlin & 63) * 2 + feat) * NG * NG;

  if (nbr <= 1 && ncb <= 1) {
    // fast path: <=2 groups per side -> 4 register accumulators
    float siv[4]; bool rhiv[4];
    #pragma unroll
    for (int v = 0; v < 4; ++v) {
      siv[v] = sA[ri0 + v];
      rhiv[v] = (i0 + ri0 + v) >= s_r;
    }
    float a00 = 0.f, a01 = 0.f, a10 = 0.f, a11 = 0.f;
    #pragma unroll
    for (int c = 0; c < 4; ++c) {
      int rj = c * 16 + m;
      float sb = sB[rj];
      float lo = 0.f, hi = 0.f;
      #pragma unroll
      for (int v = 0; v < 4; ++v) {
        float d = fmaxf(siv[v] + sb - 2.f * acc[c][v], 0.f);
        float K = __expf(-0.01f * d) + __expf(-0.1f * d) + __expf(-d)
                + __expf(-10.f * d) + __expf(-100.f * d);
        if (diag) {
          int ri = ri0 + v;
          K = (ri > rj) ? 0.f : (ri == rj) ? 5.f : K;
        }
        float kh = rhiv[v] ? K : 0.f;
        hi += kh; lo += K - kh;
      }
      bool chi = (j0 + rj) >= s_c;
      float loH = chi ? lo : 0.f;
      float hiH = chi ? hi : 0.f;
      a00 += lo - loH; a01 += loH;
      a10 += hi - hiH; a11 += hiH;
    }
    #pragma unroll
    for (int o = 32; o > 0; o >>= 1) {
      a00 += __shfl_down(a00, o); a01 += __shfl_down(a01, o);
      a10 += __shfl_down(a10, o); a11 += __shfl_down(a11, o);
    }
    if (L == 0) {
      if (a00 != 0.f)
        atomicAdd(&gsp[gr0 * NG + gc0], (u64)(long long)llroundf(a00 * 65536.f));
      if (a01 != 0.f && gc1 < 16)
        atomicAdd(&gsp[gr0 * NG + gc1], (u64)(long long)llroundf(a01 * 65536.f));
      if (a10 != 0.f && gr1 < 16)
        atomicAdd(&gsp[gr1 * NG + gc0], (u64)(long long)llroundf(a10 * 65536.f));
      if (a11 != 0.f && gr1 < 16 && gc1 < 16)
        atomicAdd(&gsp[gr1 * NG + gc1], (u64)(long long)llroundf(a11 * 65536.f));
    }
  } else {
    // rare fallback: per-element group scan + global fx atomics (correctness)
    int giv[4]; float siv[4];
    #pragma unroll
    for (int v = 0; v < 4; ++v) {
      int idx = i0 + ri0 + v;
      int g = 0;
      #pragma unroll
      for (int k = 1; k <= 16; ++k) g += (offs[k] <= idx) ? 1 : 0;
      giv[v] = g;
      siv[v] = sA[ri0 + v];
    }
    #pragma unroll
    for (int c = 0; c < 4; ++c) {
      int rj = c * 16 + m;
      int jdx = j0 + rj;
      int gj = 0;
      #pragma unroll
      for (int k = 1; k <= 16; ++k) gj += (offs[k] <= jdx) ? 1 : 0;
      float sb = sB[rj];
      #pragma unroll
      for (int v = 0; v < 4; ++v) {
        int ri = ri0 + v;
        if (giv[v] < 16 && gj < 16 && !(diag && ri > rj)) {
          float K;
          if (diag && ri == rj) K = 5.f;
          else {
            float d = fmaxf(siv[v] + sb - 2.f * acc[c][v], 0.f);
            K = __expf(-0.01f * d) + __expf(-0.1f * d) + __expf(-d)
              + __expf(-10.f * d) + __expf(-100.f * d);
          }
          u32 kf = (u32)(K * 65536.f + 0.5f);
          atomicAdd(&gsp[giv[v] * NG + gj], (u64)kf);
        }
      }
    }
  }
}

// ----------------------------------------- hsic partials: tr(KL), u^T M v
extern "C" __global__ __launch_bounds__(256) void k_hsic(
    const u64* __restrict__ U64, const float* __restrict__ Mf32, u64* SA) {
  __shared__ float red[8];
  __shared__ float ush[32], vsh[D];
  int p = blockIdx.y;
  int k0 = blockIdx.x * 32;
  int t = threadIdx.x;
  vsh[t] = fxToF(U64[(2 * p + 1) * D + t]);
  if (t < 32) ush[t] = fxToF(U64[(2 * p) * D + k0 + t]);
  __syncthreads();
  const float* M0 = Mf32 + (size_t)(0 * 2 + p) * D * D;
  const float* M1 = Mf32 + (size_t)(1 * 2 + p) * D * D;
  const float* M2 = Mf32 + (size_t)(2 * 2 + p) * D * D;
  const float* M3 = Mf32 + (size_t)(3 * 2 + p) * D * D;
  float trkl = 0.f, cr = 0.f;
  #pragma unroll 4
  for (int k = 0; k < 32; ++k) {
    size_t off = (size_t)(k0 + k) * D + t;
    float mv = M0[off] + M1[off] + M2[off] + M3[off];
    trkl += mv * mv;
    cr += ush[k] * mv;
  }
  cr *= vsh[t];
  #pragma unroll
  for (int o = 32; o > 0; o >>= 1) { trkl += __shfl_down(trkl, o); cr += __shfl_down(cr, o); }
  if ((t & 63) == 0) { red[t >> 6] = trkl; red[4 + (t >> 6)] = cr; }
  __syncthreads();
  if (t == 0) gAddFx(&SA[10 + p], red[0] + red[1] + red[2] + red[3]);
  if (t == 64) gAddFx(&SA[12 + p], red[4] + red[5] + red[6] + red[7]);
}

// ----------------------------------------------------------------- finalize
extern "C" __global__ __launch_bounds__(256) void k_final(
    const u64* SA, const u64* GCU, const u64* GSP,
    const u64* U64, float* out, int B) {
  __shared__ float red[8];
  __shared__ float gssh[2 * NG * NG];
  int t = threadIdx.x;
  for (int e = t; e < 2 * NG * NG; e += 256) {
    u64 ssum = 0;
    int f = e >> 8, idx = e & 255;
    for (int cpy = 0; cpy < 64; ++cpy)
      ssum += GSP[((size_t)cpy * 2 + f) * NG * NG + idx];
    gssh[e] = (float)((double)ssum * (1.0 / 65536.0));
  }
  __syncthreads();

  float n = (float)B;
  float hs[2];
  for (int p = 0; p < 2; ++p) {
    float ut = fxToF(U64[(2 * p) * D + t]);
    float vt = fxToF(U64[(2 * p + 1) * D + t]);
    float uu = ut * ut, vv = vt * vt;
    #pragma unroll
    for (int o = 32; o > 0; o >>= 1) { uu += __shfl_down(uu, o); vv += __shfl_down(vv, o); }
    __syncthreads();
    if ((t & 63) == 0) { red[t >> 6] = uu; red[4 + (t >> 6)] = vv; }
    __syncthreads();
    float uus = red[0] + red[1] + red[2] + red[3];
    float vvs = red[4] + red[5] + red[6] + red[7];
    float trkl = (float)((double)(long long)SA[10 + p] * (double)IFX32);
    float cr   = (float)((double)(long long)SA[12 + p] * (double)IFX32);
    hs[p] = (trkl - (2.f / n) * cr + uus * vvs / (n * n))
          / ((n - 1.f) * (n - 1.f));
    __syncthreads();
  }
  if (t == 0) {
    float msum = fmaxf((float)SA[5], 1.f);
    float f1 = fxToF(SA[0]) / msum;
    float f2 = fxToF(SA[1]) / msum;
    float f3 = fxToF(SA[2]) / msum;
    float cesv = fxToF(SA[3]) / msum;
    float cest = fxToF(SA[4]) / msum;
    float mmd[2];
    for (int f = 0; f < 2; ++f) {
      float loss = 0.f, cntv = 0.f;
      for (int lab = 0; lab < 4; ++lab)
        for (int d1 = 0; d1 < 4; ++d1)
          for (int d2 = d1 + 1; d2 < 4; ++d2) {
            int a = lab * 4 + d1, b = lab * 4 + d2;
            float n1 = (float)GCU[a], n2 = (float)GCU[b];
            if (n1 > 1.f && n2 > 1.f) {
              float g11 = 2.f * gssh[f * 256 + a * NG + a] - 5.f * n1;
              float g22 = 2.f * gssh[f * 256 + b * NG + b] - 5.f * n2;
              float g12 = gssh[f * 256 + a * NG + b];
              loss += g11 / (fmaxf(n1, 1.f) * fmaxf(n1, 1.f))
                    + g22 / (fmaxf(n2, 1.f) * fmaxf(n2, 1.f))
                    - 2.f * g12 / fmaxf(n1 * n2, 1.f);
              cntv += 1.f;
            }
          }
      mmd[f] = loss / fmaxf(cntv, 1.f);
    }
    double rs = ((double)(long long)SA[6] + (double)(long long)SA[7])
              * (double)IFX32;
    float recon = (float)(rs / ((double)B * (double)H));
    float total = 0.4f * f1 + 0.3f * f2 + 0.3f * f3
                + 0.1f * (cesv + cest + mmd[0] + mmd[1])
                + 0.1f * (hs[0] + hs[1])
                + recon;
    out[0] = total;
  }
}

// ---------------------------------------------------------------------------
extern "C" void kernel_launch(void* const* d_in, const int* in_sizes, int n_in,
                              void* d_out, int out_size, void* d_ws, size_t ws_size,
                              hipStream_t stream) {
  const float* l1  = (const float*)d_in[0];
  const int*   y1  = (const int*)d_in[1];
  const float* l2  = (const float*)d_in[2];
  const int*   y2  = (const int*)d_in[3];
  const float* l3  = (const float*)d_in[4];
  const int*   y3  = (const int*)d_in[5];
  const float* cv  = (const float*)d_in[6];
  const float* sv  = (const float*)d_in[7];
  const float* ct  = (const float*)d_in[8];
  const float* st  = (const float*)d_in[9];
  const float* vsv = (const float*)d_in[10];
  const float* vst = (const float*)d_in[11];
  const int*   dom = (const int*)d_in[12];
  const void*  mask= d_in[13];
  const float* ir  = (const float*)d_in[14];
  const float* io  = (const float*)d_in[15];
  const float* trc = (const float*)d_in[16];
  const float* to  = (const float*)d_in[17];
  int B = in_sizes[1];                        // 4096

  // workspace: u64 accumulators (zeroed) then scratch
  u64* SA  = (u64*)d_ws;                      // 32 slots
  u64* GCU = SA + 32;                         // 16
  u64* U64 = GCU + 16;                        // 4*256
  u64* GSP = U64 + 4 * D;                     // 64*2*256
  u64* zend = GSP + 64 * 2 * NG * NG;
  size_t zeroBytes = (size_t)((char*)zend - (char*)d_ws);     // ~270 KB
  unsigned short* bf  = (unsigned short*)zend;                // 2*B*D bf16
  unsigned short* bnT = bf + 2 * (size_t)B * D;               // 4*D*B bf16
  float* Mf32 = (float*)(bnT + 4 * (size_t)D * B);            // 8*D*D f32
  int*   gid = (int*)(Mf32 + 8 * (size_t)D * D);              // B
  float* sq  = (float*)(gid + B);             // 2*B
  float* inv = sq + 2 * B;                    // 4*B
  int*   perm = (int*)(inv + 4 * B);          // B
  float* sqp  = (float*)(perm + B);           // 2*B (permuted sq)
  int*   OFF  = (int*)(sqp + 2 * B);          // 18 group offsets
  u32*   CNTB = (u32*)(OFF + 18);             // NA*17 per-block counts

  int NA = B / 256;                           // 16   prep+cls blocks
  int NB = B / 8;                             // 512  rowstats blocks (32 rows)
  int NC = 1024;                              // recon blocks (512 per half)
  int N4 = B * H / 4;

  hipMemsetAsync(d_ws, 0, zeroBytes, stream);
  k_pre<<<NA + NB + NC, 256, 0, stream>>>(
      mask, y1, dom, l1, l2, l3, y2, y3, vsv, vst,
      cv, sv, ct, st, ir, io, trc, to,
      SA, GCU, U64, gid, sq, inv, bf, CNTB, B, N4, NA, NB);
  int NTR = B / 4;                            // transpose blocks (1024)
  k_mid<<<NA + NTR, 256, 0, stream>>>(CNTB, gid, sq, cv, sv, ct, st, inv,
                                      perm, sqp, OFF, bnT, B, NA);
  int NT = B / 64;
  int nmmd = 2 * (NT * (NT + 1) / 2);         // 4160
  k_big<<<128 + nmmd, 256, 0, stream>>>(bf, sqp, perm, OFF, bnT, Mf32, GSP, B);
  k_hsic<<<dim3(8, 2), 256, 0, stream>>>(U64, Mf32, SA);
  k_final<<<1, 256, 0, stream>>>(SA, GCU, GSP, U64, (float*)d_out, B);
}

// Round 7
// 203.619 us; speedup vs baseline: 1.3924x; 1.0322x over previous
//
#include <hip/hip_runtime.h>
#include <hip/hip_bf16.h>

// ---------------------------------------------------------------------------
// CausalCrisisLoss on MI355X.  R11 = R7 (best verified, 207.9us) + exp-gating.
//  * k_pre  = detect+prep+cls (A) | rowstats+u (B: 8-row ILP) | recon (C)
//  * k_mid  = [0,NA): ballot-rank counting sort | [NA,..): transpose+normalize
//  * k_big  = role M [0,64): Chat^T Shat bf16 MFMA, K-split 2, f32 out
//             role T [64,..): sorted-row 64x64 Gram tiles, register MMD
//             epilogue with magnitude-gated RBF terms:
//               exp(-g*d) dropped when g*d > 21 (term < 8e-10, invisible at
//               fx16 resolution 1.5e-5; wave-uniform execz skip for this
//               data where d ~= 512). 5 exps/element -> 1 for large d.
//  * k_hsic, k_final unchanged.
// No float atomics anywhere: u64 fx2^32 / fx2^16 native global atomics.
// Bit-deterministic across replays.
// ---------------------------------------------------------------------------

typedef short bf16x8 __attribute__((ext_vector_type(8)));
typedef float f32x4 __attribute__((ext_vector_type(4)));
typedef unsigned long long u64;
typedef unsigned int u32;

static constexpr int D = 256;
static constexpr int H = 768;
static constexpr int NG = 16;
static constexpr float FX32 = 4294967296.f;
static constexpr float IFX32 = 2.3283064365386963e-10f;

__device__ inline void gAddFx(u64* p, float v) {
  long long q = (long long)llroundf(v * FX32);
  atomicAdd(p, (u64)q);                           // native global_atomic_add_x2
}
__device__ inline float fxToF(u64 v) { return (float)(long long)v * IFX32; }

// multi-gamma RBF kernel sum with magnitude gating (see header comment)
__device__ inline float rbf5(float d) {
  float K = __expf(-0.01f * d);
  if (d <= 210.f) {
    K += __expf(-0.1f * d);
    if (d <= 21.f)
      K += __expf(-d) + __expf(-10.f * d) + __expf(-100.f * d);
  }
  return K;
}

__device__ inline float focal_n(const float* x, int n, int tgt,
                                float s_over_n, float oms) {
  float mx = x[0];
  for (int c = 1; c < n; ++c) mx = fmaxf(mx, x[c]);
  float se = 0.f, sx = 0.f;
  for (int c = 0; c < n; ++c) { se += __expf(x[c] - mx); sx += x[c]; }
  float logZ = mx + __logf(se);
  float ce = logZ - oms * x[tgt] - s_over_n * sx;
  float pt = __expf(x[tgt] - logZ);
  float om = 1.f - pt;
  return ce * om * om;
}

// ============================================================== k_pre (fused)
// role A [0,NA):        mode-detect + maskf/gid/counts + cls (interleaved red)
// role B [NA,NA+NB):    per-row norms (8-row ILP batch), bf16 copy, sq, inv,
//                       u-partials (LDS cross-wave reduce)
// role C [NA+NB,+NC):   recon MSE, static chunks, dual-unrolled loads
extern "C" __global__ __launch_bounds__(256) void k_pre(
    const void* __restrict__ mask, const int* __restrict__ y1,
    const int* __restrict__ dom,
    const float* __restrict__ l1, const float* __restrict__ l2,
    const float* __restrict__ l3, const int* __restrict__ y2,
    const int* __restrict__ y3,
    const float* __restrict__ vsv, const float* __restrict__ vst,
    const float* __restrict__ cv, const float* __restrict__ sv,
    const float* __restrict__ ct, const float* __restrict__ st,
    const float* __restrict__ ir, const float* __restrict__ io,
    const float* __restrict__ trc, const float* __restrict__ to,
    u64* SA, u64* GCU, u64* U64,
    int* gid, float* sq, float* inv, unsigned short* bf, u32* CNTB,
    int B, int N4, int NA, int NB) {
  __shared__ u32 sh3[3];
  __shared__ u32 cnt[17];
  __shared__ int redi[4];
  __shared__ float redf[4];
  __shared__ float redf5[5][4];
  __shared__ float ub[4][64][4];
  int bid = blockIdx.x;
  int t = threadIdx.x;

  if (bid < NA) {
    // ---------------- role A: detect + prep + cls ----------------
    if (t < 3) sh3[t] = 0;
    if (t < 17) cnt[t] = 0;
    __syncthreads();
    u32 a = 0, b2 = 0, cd = 0;
    if (t * 16 + 15 < B) {
      uint4 wv = ((const uint4*)mask)[t];
      u32 ws[4] = {wv.x, wv.y, wv.z, wv.w};
      #pragma unroll
      for (int j = 0; j < 4; ++j) {
        a |= ws[j] & 0xffu; b2 |= ws[j] & 0xff00u; cd |= ws[j] & 0xffff0000u;
      }
    }
    if (a) atomicOr(&sh3[0], 1u);
    if (b2) atomicOr(&sh3[1], 1u);
    if (cd) atomicOr(&sh3[2], 1u);
    __syncthreads();
    int mode;
    if ((sh3[1] | sh3[2]) == 0) mode = 0;          // int32 0/1
    else if (sh3[0] == 0 && sh3[1] == 0) mode = 1; // f32
    else mode = 2;                                 // u8
    int r = bid * 256 + t;
    int mi = 0;
    float s[5] = {0.f, 0.f, 0.f, 0.f, 0.f};
    if (r < B) {
      if (mode == 0)      mi = ((const int*)mask)[r] ? 1 : 0;
      else if (mode == 1) mi = (((const float*)mask)[r] != 0.f) ? 1 : 0;
      else                mi = ((const unsigned char*)mask)[r] ? 1 : 0;
      int g = -1;
      if (mi) { g = y1[r] * 4 + dom[r]; atomicAdd(&cnt[g], 1u); }
      else atomicAdd(&cnt[16], 1u);
      gid[r] = g;
      if (mi) {
        float x[6];
        for (int c = 0; c < 4; ++c) x[c] = l1[r * 4 + c];
        s[0] = focal_n(x, 4, y1[r], 0.1f / 4.f, 0.9f);
        for (int c = 0; c < 6; ++c) x[c] = l2[r * 6 + c];
        s[1] = focal_n(x, 6, y2[r], 0.1f / 6.f, 0.9f);
        for (int c = 0; c < 3; ++c) x[c] = l3[r * 3 + c];
        s[2] = focal_n(x, 3, y3[r], 0.1f / 3.f, 0.9f);
        int d = dom[r];
        for (int c = 0; c < 4; ++c) x[c] = vsv[r * 4 + c];
        {
          float mx = fmaxf(fmaxf(x[0], x[1]), fmaxf(x[2], x[3]));
          float se = __expf(x[0]-mx)+__expf(x[1]-mx)+__expf(x[2]-mx)+__expf(x[3]-mx);
          s[3] = mx + __logf(se) - x[d];
        }
        for (int c = 0; c < 4; ++c) x[c] = vst[r * 4 + c];
        {
          float mx = fmaxf(fmaxf(x[0], x[1]), fmaxf(x[2], x[3]));
          float se = __expf(x[0]-mx)+__expf(x[1]-mx)+__expf(x[2]-mx)+__expf(x[3]-mx);
          s[4] = mx + __logf(se) - x[d];
        }
      }
    }
    int v = mi;
    #pragma unroll
    for (int o = 32; o > 0; o >>= 1) {
      v += __shfl_down(v, o);
      #pragma unroll
      for (int k = 0; k < 5; ++k) s[k] += __shfl_down(s[k], o);
    }
    if ((t & 63) == 0) {
      redi[t >> 6] = v;
      #pragma unroll
      for (int k = 0; k < 5; ++k) redf5[k][t >> 6] = s[k];
    }
    __syncthreads();
    if (t == 0) {
      atomicAdd(&SA[5], (u64)(redi[0] + redi[1] + redi[2] + redi[3]));
      #pragma unroll
      for (int k = 0; k < 5; ++k)
        gAddFx(&SA[k], redf5[k][0] + redf5[k][1] + redf5[k][2] + redf5[k][3]);
    }
    if (t < NG && cnt[t]) atomicAdd(&GCU[t], (u64)cnt[t]);
    if (t < 17) CNTB[bid * 17 + t] = cnt[t];
  } else if (bid < NA + NB) {
    // ---------------- role B: rowstats + u (8-row ILP batch) ----------------
    int b = bid - NA;
    int perF = NB >> 2;                      // blocks per feature
    int f = b / perF;                        // 0..3  (cv, sv, ct, st)
    int rb = b - f * perF;                   // 32-row chunk index
    const float* p = (f == 0) ? cv : (f == 1) ? sv : (f == 2) ? ct : st;
    int w = t >> 6, L = t & 63;
    int rbase = rb * 32 + w * 8;
    float4 vv[8];
    #pragma unroll
    for (int i = 0; i < 8; ++i)
      vv[i] = ((const float4*)(p + (size_t)(rbase + i) * D))[L];
    float ss[8];
    #pragma unroll
    for (int i = 0; i < 8; ++i)
      ss[i] = vv[i].x * vv[i].x + vv[i].y * vv[i].y
            + vv[i].z * vv[i].z + vv[i].w * vv[i].w;
    #pragma unroll
    for (int o = 32; o > 0; o >>= 1) {
      #pragma unroll
      for (int i = 0; i < 8; ++i) ss[i] += __shfl_down(ss[i], o);
    }
    #pragma unroll
    for (int i = 0; i < 8; ++i) ss[i] = __shfl(ss[i], 0);
    float up0 = 0.f, up1 = 0.f, up2 = 0.f, up3 = 0.f;
    #pragma unroll
    for (int i = 0; i < 8; ++i) {
      int r = rbase + i;
      float iv = 1.f / fmaxf(sqrtf(ss[i]), 1e-12f);
      if ((f & 1) == 0) {
        int fi = f >> 1;
        alignas(8) __hip_bfloat16 hb[4];
        hb[0] = __float2bfloat16(vv[i].x); hb[1] = __float2bfloat16(vv[i].y);
        hb[2] = __float2bfloat16(vv[i].z); hb[3] = __float2bfloat16(vv[i].w);
        *(uint2*)(bf + ((size_t)fi * B + r) * D + L * 4) = *(uint2*)hb;
        if (L == 0) sq[fi * B + r] = ss[i];
      }
      if (L == 0) inv[f * B + r] = iv;
      up0 += vv[i].x * iv; up1 += vv[i].y * iv;
      up2 += vv[i].z * iv; up3 += vv[i].w * iv;
    }
    ub[w][L][0] = up0; ub[w][L][1] = up1; ub[w][L][2] = up2; ub[w][L][3] = up3;
    __syncthreads();
    if (t < 64) {
      u64* Uf = U64 + f * D + 4 * t;
      #pragma unroll
      for (int j = 0; j < 4; ++j) {
        float s4 = ub[0][t][j] + ub[1][t][j] + ub[2][t][j] + ub[3][t][j];
        gAddFx(Uf + j, s4);
      }
    }
  } else {
    // ---------------- role C: recon (static chunks, dual loads) ----------------
    int cidx = bid - (NA + NB);
    int j = cidx >> 9;                       // 0/1: img / txt  (512 blocks ea)
    int cb = cidx & 511;
    const float4* A  = (const float4*)(j ? trc : ir);
    const float4* Bp = (const float4*)(j ? to : io);
    int CH = (N4 + 511) >> 9;                // per-block chunk (1536 @ B=4096)
    int base = cb * CH;
    int end = min(base + CH, N4);
    float acc = 0.f;
    int idx = base + t;
    for (; idx + 256 < end; idx += 512) {
      float4 a0 = A[idx],       b0 = Bp[idx];
      float4 a1 = A[idx + 256], b1 = Bp[idx + 256];
      float dx0 = a0.x-b0.x, dy0 = a0.y-b0.y, dz0 = a0.z-b0.z, dw0 = a0.w-b0.w;
      float dx1 = a1.x-b1.x, dy1 = a1.y-b1.y, dz1 = a1.z-b1.z, dw1 = a1.w-b1.w;
      acc += dx0*dx0 + dy0*dy0 + dz0*dz0 + dw0*dw0
           + dx1*dx1 + dy1*dy1 + dz1*dz1 + dw1*dw1;
    }
    if (idx < end) {
      float4 a = A[idx], b = Bp[idx];
      float dx = a.x-b.x, dy = a.y-b.y, dz = a.z-b.z, dw = a.w-b.w;
      acc += dx*dx + dy*dy + dz*dz + dw*dw;
    }
    #pragma unroll
    for (int o = 32; o > 0; o >>= 1) acc += __shfl_down(acc, o);
    if ((t & 63) == 0) redf[t >> 6] = acc;
    __syncthreads();
    if (t == 0) gAddFx(&SA[6 + j], redf[0] + redf[1] + redf[2] + redf[3]);
  }
}

// ============================================================== k_mid
// [0,NA):   deterministic stable counting sort by gid via wave ballots
// [NA,..):  transpose + normalize features -> bnT[4][256][B] bf16
extern "C" __global__ __launch_bounds__(256) void k_mid(
    const u32* __restrict__ CNTB, const int* __restrict__ gid,
    const float* __restrict__ sq,
    const float* __restrict__ cv, const float* __restrict__ sv,
    const float* __restrict__ ct, const float* __restrict__ st,
    const float* __restrict__ inv,
    int* __restrict__ perm, float* __restrict__ sqp, int* __restrict__ OFF,
    unsigned short* __restrict__ bnT, int B, int NA) {
  __shared__ float ld[64 * 65];              // transpose tile (16.6 KB)
  __shared__ u32 cbs[17], tots[17], wcnt[4][17];
  __shared__ u32 base[18];
  int b = blockIdx.x, t = threadIdx.x;

  if (b < NA) {
    // ---------------- sort ----------------
    if (t < 68) ((u32*)wcnt)[t] = 0;
    if (t < 17) {
      u32 cb = 0, tot = 0;
      for (int b2 = 0; b2 < NA; ++b2) {
        u32 c = CNTB[b2 * 17 + t];
        cb += (b2 < b) ? c : 0u;
        tot += c;
      }
      cbs[t] = cb; tots[t] = tot;
    }
    int r = b * 256 + t;
    int g = 16;
    if (r < B) { int gg = gid[r]; g = (gg < 0) ? 16 : gg; }
    __syncthreads();
    if (t == 0) {
      u32 s = 0;
      for (int g2 = 0; g2 < 17; ++g2) { base[g2] = s; s += tots[g2]; }
      base[17] = s;
    }
    // 5-bit ballot same-group mask (all lanes participate)
    u64 msk = ~0ull;
    #pragma unroll
    for (int bit = 0; bit < 5; ++bit) {
      int bv = (g >> bit) & 1;
      u64 bl = __ballot(bv);
      msk &= bv ? bl : ~bl;
    }
    int lane = t & 63, w = t >> 6;
    int rwave = __popcll(msk & ((1ull << lane) - 1ull));
    if (rwave == 0) wcnt[w][g] = (u32)__popcll(msk);
    __syncthreads();
    if (r < B) {
      int rank = rwave;
      for (int w2 = 0; w2 < 4; ++w2) if (w2 < w) rank += (int)wcnt[w2][g];
      int pos = (int)(base[g] + cbs[g]) + rank;
      perm[pos] = r;
      sqp[pos] = sq[r];
      sqp[B + pos] = sq[B + r];
    }
    if (b == 0 && t < 18) OFF[t] = (int)base[t];
  } else {
    // ---------------- transpose + normalize ----------------
    int TPF = (B >> 6) * 4;                  // tiles per feature
    int tb = b - NA;
    int fm = tb / TPF, tile = tb - fm * TPF;
    int it = tile >> 2, at = tile & 3;
    const float* src = (fm == 0) ? cv : (fm == 1) ? sv : (fm == 2) ? ct : st;
    const float* ivf = inv + (size_t)fm * B;
    int i0 = it * 64, a0 = at * 64;
    for (int e = t; e < 1024; e += 256) {
      int i = e >> 4, c4 = e & 15;
      float4 v = ((const float4*)(src + (size_t)(i0 + i) * D))[at * 16 + c4];
      float ivv = ivf[i0 + i];
      ld[i * 65 + c4 * 4 + 0] = v.x * ivv;
      ld[i * 65 + c4 * 4 + 1] = v.y * ivv;
      ld[i * 65 + c4 * 4 + 2] = v.z * ivv;
      ld[i * 65 + c4 * 4 + 3] = v.w * ivv;
    }
    __syncthreads();
    unsigned short* dst = bnT + (size_t)fm * D * B;
    for (int e = t; e < 512; e += 256) {
      int a = e >> 3, ic = e & 7;
      alignas(16) unsigned short h[8];
      #pragma unroll
      for (int j = 0; j < 8; ++j) {
        __hip_bfloat16 hb = __float2bfloat16(ld[(ic * 8 + j) * 65 + a]);
        h[j] = *(unsigned short*)&hb;
      }
      *(uint4*)(dst + (size_t)(a0 + a) * B + i0 + ic * 8) = *(uint4*)h;
    }
  }
}

// ============================================================== k_big (fused)
// role M [0,64): M = Chat^T Shat bf16 MFMA, 64x64 tiles, K-split 2, f32 out
// role T [64, 64+2*2080): sorted-row 64x64 Gram tiles, register MMD epilogue
extern "C" __global__ __launch_bounds__(256) void k_big(
    const unsigned short* __restrict__ bf, const float* __restrict__ sqp,
    const int* __restrict__ perm, const int* __restrict__ OFF,
    const unsigned short* __restrict__ bnT, float* __restrict__ Mf32,
    u64* GSP, int B) {
  __shared__ __align__(16) char smem[17536];
  unsigned short* Ab = (unsigned short*)smem;               // 8 KB
  unsigned short* Bb = (unsigned short*)(smem + 8192);      // 8 KB
  int bid = blockIdx.x;
  int tid = threadIdx.x;
  int w = tid >> 6, L = tid & 63, m = L & 15, q = L >> 4;
  int r0 = tid >> 3, ck = tid & 7;
  int swz = (ck ^ (r0 & 7)) * 8;
  int ar = w * 16 + m;

  if (bid < 64) {
    // ---------------- role M: bf16 MFMA GEMM ----------------
    int half = bid & 1, bb = (bid >> 1) & 3, ab = (bid >> 3) & 3, p = (bid >> 5) & 1;
    const unsigned short* Abase = bnT + (size_t)(2 * p) * D * B;
    const unsigned short* Bbase = bnT + (size_t)(2 * p + 1) * D * B;
    size_t kof = (size_t)half * (B >> 1) + ck * 8;
    const uint4* gA0 = (const uint4*)(Abase + (size_t)(ab * 64 + r0) * B + kof);
    const uint4* gA1 = (const uint4*)(Abase + (size_t)(ab * 64 + r0 + 32) * B + kof);
    const uint4* gB0 = (const uint4*)(Bbase + (size_t)(bb * 64 + r0) * B + kof);
    const uint4* gB1 = (const uint4*)(Bbase + (size_t)(bb * 64 + r0 + 32) * B + kof);
    uint4* dA0 = (uint4*)&Ab[r0 * 64 + swz];
    uint4* dA1 = (uint4*)&Ab[(r0 + 32) * 64 + swz];
    uint4* dB0 = (uint4*)&Bb[r0 * 64 + swz];
    uint4* dB1 = (uint4*)&Bb[(r0 + 32) * 64 + swz];
    f32x4 acc[4] = {{0.f,0.f,0.f,0.f},{0.f,0.f,0.f,0.f},
                    {0.f,0.f,0.f,0.f},{0.f,0.f,0.f,0.f}};
    int nh = B >> 7;                         // rounds of K=64 per half
    for (int hq = 0; hq < nh; ++hq) {
      *dA0 = gA0[hq * 8]; *dA1 = gA1[hq * 8];
      *dB0 = gB0[hq * 8]; *dB1 = gB1[hq * 8];
      __syncthreads();
      #pragma unroll
      for (int kk = 0; kk < 2; ++kk) {
        bf16x8 aF = *(const bf16x8*)&Ab[ar * 64 + (((kk * 4 + q) ^ (ar & 7)) * 8)];
        #pragma unroll
        for (int c = 0; c < 4; ++c) {
          int br = c * 16 + m;
          bf16x8 bF = *(const bf16x8*)&Bb[br * 64 + (((kk * 4 + q) ^ (br & 7)) * 8)];
          acc[c] = __builtin_amdgcn_mfma_f32_16x16x32_bf16(aF, bF, acc[c], 0, 0, 0);
        }
      }
      if (hq < nh - 1) __syncthreads();
    }
    // plain f32 stores: this block exclusively owns its output tile
    float* Mo = Mf32 + (size_t)(half * 2 + p) * D * D;
    int ri0 = w * 16 + q * 4;
    #pragma unroll
    for (int c = 0; c < 4; ++c) {
      #pragma unroll
      for (int v = 0; v < 4; ++v)
        Mo[(size_t)(ab * 64 + ri0 + v) * D + bb * 64 + c * 16 + m] = acc[c][v];
    }
    return;
  }

  // ---------------- role T: mmd tile (sorted rows) ----------------
  float* sA = (float*)(smem + 16384);                       // 256 B
  float* sB = (float*)(smem + 16640);                       // 256 B
  int*   pA = (int*)(smem + 16896);                         // 256 B
  int*   pB = (int*)(smem + 17152);                         // 256 B
  int*   offs = (int*)(smem + 17408);                       // 72 B

  int idx2 = bid - 64;
  int feat = idx2 & 1;
  int tlin = idx2 >> 1;
  int NT = B / 64;
  float tf = (float)tlin;
  int ti = (int)((2.f * NT + 1.f -
                  sqrtf((2.f * NT + 1.f) * (2.f * NT + 1.f) - 8.f * tf)) * 0.5f);
  while (ti > 0 && (ti * NT - (ti * (ti - 1)) / 2) > tlin) --ti;
  while (((ti + 1) * NT - ((ti + 1) * ti) / 2) <= tlin) ++ti;
  int tj = ti + (tlin - (ti * NT - (ti * (ti - 1)) / 2));
  int i0 = ti * 64, j0 = tj * 64;
  bool diag = (ti == tj);
  const unsigned short* fb = bf + (size_t)feat * B * D;
  const float* sqf = sqp + (size_t)feat * B;

  if (tid < 64) { pA[tid] = perm[i0 + tid]; sA[tid] = sqf[i0 + tid]; }
  else if (tid < 128) { int r = tid - 64; pB[r] = perm[j0 + r]; sB[r] = sqf[j0 + r]; }
  else if (tid < 146) offs[tid - 128] = OFF[tid - 128];
  __syncthreads();

  // block-uniform group / boundary analysis
  int gr0 = 0, nbr = 0, gc0 = 0, ncb = 0;
  #pragma unroll
  for (int g = 1; g <= 17; ++g) {
    int o = offs[g];
    gr0 += (o <= i0) ? 1 : 0;
    nbr += (o > i0 && o < i0 + 64) ? 1 : 0;
    gc0 += (o <= j0) ? 1 : 0;
    ncb += (o > j0 && o < j0 + 64) ? 1 : 0;
  }
  if (gr0 == 16 || gc0 == 16) return;        // tile entirely invalid-masked
  int gr1 = gr0 + nbr;
  int gc1 = gc0 + ncb;
  int s_r = nbr ? offs[gr1] : i0 + 64;
  int s_c = ncb ? offs[gc1] : j0 + 64;

  // hoisted staging pointers (fixed row/chunk per thread; per-round imm offset)
  const uint4* gA0 = (const uint4*)(fb + (size_t)pA[r0] * D + ck * 8);
  const uint4* gA1 = (const uint4*)(fb + (size_t)pA[r0 + 32] * D + ck * 8);
  uint4* dA0 = (uint4*)&Ab[r0 * 64 + swz];
  uint4* dA1 = (uint4*)&Ab[(r0 + 32) * 64 + swz];
  const uint4* gB0 = nullptr; const uint4* gB1 = nullptr;
  uint4* dB0 = nullptr; uint4* dB1 = nullptr;
  if (!diag) {
    gB0 = (const uint4*)(fb + (size_t)pB[r0] * D + ck * 8);
    gB1 = (const uint4*)(fb + (size_t)pB[r0 + 32] * D + ck * 8);
    dB0 = (uint4*)&Bb[r0 * 64 + swz];
    dB1 = (uint4*)&Bb[(r0 + 32) * 64 + swz];
  }
  const unsigned short* Bp = diag ? Ab : Bb;

  f32x4 acc[4] = {{0.f,0.f,0.f,0.f},{0.f,0.f,0.f,0.f},
                  {0.f,0.f,0.f,0.f},{0.f,0.f,0.f,0.f}};

  for (int hq = 0; hq < 4; ++hq) {           // K rounds of 64
    *dA0 = gA0[hq * 8]; *dA1 = gA1[hq * 8];
    if (!diag) { *dB0 = gB0[hq * 8]; *dB1 = gB1[hq * 8]; }
    __syncthreads();
    #pragma unroll
    for (int kk = 0; kk < 2; ++kk) {
      bf16x8 aF = *(const bf16x8*)&Ab[ar * 64 + (((kk * 4 + q) ^ (ar & 7)) * 8)];
      #pragma unroll
      for (int c = 0; c < 4; ++c) {
        int br = c * 16 + m;
        bf16x8 bF = *(const bf16x8*)&Bp[br * 64 + (((kk * 4 + q) ^ (br & 7)) * 8)];
        acc[c] = __builtin_amdgcn_mfma_f32_16x16x32_bf16(aF, bF, acc[c], 0, 0, 0);
      }
    }
    if (hq < 3) __syncthreads();
  }

  // epilogue: C/D layout col=lane&15, row=(lane>>4)*4+reg (m89/m91).
  int ri0 = w * 16 + q * 4;
  u64* gsp = GSP + ((size_t)(tlin & 63) * 2 + feat) * NG * NG;

  if (nbr <= 1 && ncb <= 1) {
    // fast path: <=2 groups per side -> 4 register accumulators
    float siv[4]; bool rhiv[4];
    #pragma unroll
    for (int v = 0; v < 4; ++v) {
      siv[v] = sA[ri0 + v];
      rhiv[v] = (i0 + ri0 + v) >= s_r;
    }
    float a00 = 0.f, a01 = 0.f, a10 = 0.f, a11 = 0.f;
    #pragma unroll
    for (int c = 0; c < 4; ++c) {
      int rj = c * 16 + m;
      float sb = sB[rj];
      float lo = 0.f, hi = 0.f;
      #pragma unroll
      for (int v = 0; v < 4; ++v) {
        float d = fmaxf(siv[v] + sb - 2.f * acc[c][v], 0.f);
        float K = rbf5(d);
        if (diag) {
          int ri = ri0 + v;
          K = (ri > rj) ? 0.f : (ri == rj) ? 5.f : K;
        }
        float kh = rhiv[v] ? K : 0.f;
        hi += kh; lo += K - kh;
      }
      bool chi = (j0 + rj) >= s_c;
      float loH = chi ? lo : 0.f;
      float hiH = chi ? hi : 0.f;
      a00 += lo - loH; a01 += loH;
      a10 += hi - hiH; a11 += hiH;
    }
    #pragma unroll
    for (int o = 32; o > 0; o >>= 1) {
      a00 += __shfl_down(a00, o); a01 += __shfl_down(a01, o);
      a10 += __shfl_down(a10, o); a11 += __shfl_down(a11, o);
    }
    if (L == 0) {
      if (a00 != 0.f)
        atomicAdd(&gsp[gr0 * NG + gc0], (u64)(long long)llroundf(a00 * 65536.f));
      if (a01 != 0.f && gc1 < 16)
        atomicAdd(&gsp[gr0 * NG + gc1], (u64)(long long)llroundf(a01 * 65536.f));
      if (a10 != 0.f && gr1 < 16)
        atomicAdd(&gsp[gr1 * NG + gc0], (u64)(long long)llroundf(a10 * 65536.f));
      if (a11 != 0.f && gr1 < 16 && gc1 < 16)
        atomicAdd(&gsp[gr1 * NG + gc1], (u64)(long long)llroundf(a11 * 65536.f));
    }
  } else {
    // rare fallback: per-element group scan + global fx atomics (correctness)
    int giv[4]; float siv[4];
    #pragma unroll
    for (int v = 0; v < 4; ++v) {
      int idx = i0 + ri0 + v;
      int g = 0;
      #pragma unroll
      for (int k = 1; k <= 16; ++k) g += (offs[k] <= idx) ? 1 : 0;
      giv[v] = g;
      siv[v] = sA[ri0 + v];
    }
    #pragma unroll
    for (int c = 0; c < 4; ++c) {
      int rj = c * 16 + m;
      int jdx = j0 + rj;
      int gj = 0;
      #pragma unroll
      for (int k = 1; k <= 16; ++k) gj += (offs[k] <= jdx) ? 1 : 0;
      float sb = sB[rj];
      #pragma unroll
      for (int v = 0; v < 4; ++v) {
        int ri = ri0 + v;
        if (giv[v] < 16 && gj < 16 && !(diag && ri > rj)) {
          float K;
          if (diag && ri == rj) K = 5.f;
          else {
            float d = fmaxf(siv[v] + sb - 2.f * acc[c][v], 0.f);
            K = rbf5(d);
          }
          u32 kf = (u32)(K * 65536.f + 0.5f);
          atomicAdd(&gsp[giv[v] * NG + gj], (u64)kf);
        }
      }
    }
  }
}

// ----------------------------------------- hsic partials: tr(KL), u^T M v
extern "C" __global__ __launch_bounds__(256) void k_hsic(
    const u64* __restrict__ U64, const float* __restrict__ Mf32, u64* SA) {
  __shared__ float red[8];
  __shared__ float ush[32], vsh[D];
  int p = blockIdx.y;
  int k0 = blockIdx.x * 32;
  int t = threadIdx.x;
  vsh[t] = fxToF(U64[(2 * p + 1) * D + t]);
  if (t < 32) ush[t] = fxToF(U64[(2 * p) * D + k0 + t]);
  __syncthreads();
  const float* M0 = Mf32 + (size_t)p * D * D;            // half 0
  const float* M1 = Mf32 + (size_t)(2 + p) * D * D;      // half 1
  float trkl = 0.f, cr = 0.f;
  #pragma unroll 4
  for (int k = 0; k < 32; ++k) {
    float mv = M0[(size_t)(k0 + k) * D + t] + M1[(size_t)(k0 + k) * D + t];
    trkl += mv * mv;
    cr += ush[k] * mv;
  }
  cr *= vsh[t];
  #pragma unroll
  for (int o = 32; o > 0; o >>= 1) { trkl += __shfl_down(trkl, o); cr += __shfl_down(cr, o); }
  if ((t & 63) == 0) { red[t >> 6] = trkl; red[4 + (t >> 6)] = cr; }
  __syncthreads();
  if (t == 0) gAddFx(&SA[10 + p], red[0] + red[1] + red[2] + red[3]);
  if (t == 64) gAddFx(&SA[12 + p], red[4] + red[5] + red[6] + red[7]);
}

// ----------------------------------------------------------------- finalize
extern "C" __global__ __launch_bounds__(256) void k_final(
    const u64* SA, const u64* GCU, const u64* GSP,
    const u64* U64, float* out, int B) {
  __shared__ float red[8];
  __shared__ float gssh[2 * NG * NG];
  int t = threadIdx.x;
  for (int e = t; e < 2 * NG * NG; e += 256) {
    u64 ssum = 0;
    int f = e >> 8, idx = e & 255;
    for (int cpy = 0; cpy < 64; ++cpy)
      ssum += GSP[((size_t)cpy * 2 + f) * NG * NG + idx];
    gssh[e] = (float)((double)ssum * (1.0 / 65536.0));
  }
  __syncthreads();

  float n = (float)B;
  float hs[2];
  for (int p = 0; p < 2; ++p) {
    float ut = fxToF(U64[(2 * p) * D + t]);
    float vt = fxToF(U64[(2 * p + 1) * D + t]);
    float uu = ut * ut, vv = vt * vt;
    #pragma unroll
    for (int o = 32; o > 0; o >>= 1) { uu += __shfl_down(uu, o); vv += __shfl_down(vv, o); }
    __syncthreads();
    if ((t & 63) == 0) { red[t >> 6] = uu; red[4 + (t >> 6)] = vv; }
    __syncthreads();
    float uus = red[0] + red[1] + red[2] + red[3];
    float vvs = red[4] + red[5] + red[6] + red[7];
    float trkl = (float)((double)(long long)SA[10 + p] * (double)IFX32);
    float cr   = (float)((double)(long long)SA[12 + p] * (double)IFX32);
    hs[p] = (trkl - (2.f / n) * cr + uus * vvs / (n * n))
          / ((n - 1.f) * (n - 1.f));
    __syncthreads();
  }
  if (t == 0) {
    float msum = fmaxf((float)SA[5], 1.f);
    float f1 = fxToF(SA[0]) / msum;
    float f2 = fxToF(SA[1]) / msum;
    float f3 = fxToF(SA[2]) / msum;
    float cesv = fxToF(SA[3]) / msum;
    float cest = fxToF(SA[4]) / msum;
    float mmd[2];
    for (int f = 0; f < 2; ++f) {
      float loss = 0.f, cntv = 0.f;
      for (int lab = 0; lab < 4; ++lab)
        for (int d1 = 0; d1 < 4; ++d1)
          for (int d2 = d1 + 1; d2 < 4; ++d2) {
            int a = lab * 4 + d1, b = lab * 4 + d2;
            float n1 = (float)GCU[a], n2 = (float)GCU[b];
            if (n1 > 1.f && n2 > 1.f) {
              float g11 = 2.f * gssh[f * 256 + a * NG + a] - 5.f * n1;
              float g22 = 2.f * gssh[f * 256 + b * NG + b] - 5.f * n2;
              float g12 = gssh[f * 256 + a * NG + b];
              loss += g11 / (fmaxf(n1, 1.f) * fmaxf(n1, 1.f))
                    + g22 / (fmaxf(n2, 1.f) * fmaxf(n2, 1.f))
                    - 2.f * g12 / fmaxf(n1 * n2, 1.f);
              cntv += 1.f;
            }
          }
      mmd[f] = loss / fmaxf(cntv, 1.f);
    }
    double rs = ((double)(long long)SA[6] + (double)(long long)SA[7])
              * (double)IFX32;
    float recon = (float)(rs / ((double)B * (double)H));
    float total = 0.4f * f1 + 0.3f * f2 + 0.3f * f3
                + 0.1f * (cesv + cest + mmd[0] + mmd[1])
                + 0.1f * (hs[0] + hs[1])
                + recon;
    out[0] = total;
  }
}

// ---------------------------------------------------------------------------
extern "C" void kernel_launch(void* const* d_in, const int* in_sizes, int n_in,
                              void* d_out, int out_size, void* d_ws, size_t ws_size,
                              hipStream_t stream) {
  const float* l1  = (const float*)d_in[0];
  const int*   y1  = (const int*)d_in[1];
  const float* l2  = (const float*)d_in[2];
  const int*   y2  = (const int*)d_in[3];
  const float* l3  = (const float*)d_in[4];
  const int*   y3  = (const int*)d_in[5];
  const float* cv  = (const float*)d_in[6];
  const float* sv  = (const float*)d_in[7];
  const float* ct  = (const float*)d_in[8];
  const float* st  = (const float*)d_in[9];
  const float* vsv = (const float*)d_in[10];
  const float* vst = (const float*)d_in[11];
  const int*   dom = (const int*)d_in[12];
  const void*  mask= d_in[13];
  const float* ir  = (const float*)d_in[14];
  const float* io  = (const float*)d_in[15];
  const float* trc = (const float*)d_in[16];
  const float* to  = (const float*)d_in[17];
  int B = in_sizes[1];                        // 4096

  // workspace: u64 accumulators (zeroed) then scratch
  u64* SA  = (u64*)d_ws;                      // 32 slots
  u64* GCU = SA + 32;                         // 16
  u64* U64 = GCU + 16;                        // 4*256
  u64* GSP = U64 + 4 * D;                     // 64*2*256
  u64* zend = GSP + 64 * 2 * NG * NG;
  size_t zeroBytes = (size_t)((char*)zend - (char*)d_ws);     // ~270 KB
  unsigned short* bf  = (unsigned short*)zend;                // 2*B*D bf16
  unsigned short* bnT = bf + 2 * (size_t)B * D;               // 4*D*B bf16
  float* Mf32 = (float*)(bnT + 4 * (size_t)D * B);            // 4*D*D f32
  int*   gid = (int*)(Mf32 + 4 * (size_t)D * D);              // B
  float* sq  = (float*)(gid + B);             // 2*B
  float* inv = sq + 2 * B;                    // 4*B
  int*   perm = (int*)(inv + 4 * B);          // B
  float* sqp  = (float*)(perm + B);           // 2*B (permuted sq)
  int*   OFF  = (int*)(sqp + 2 * B);          // 18 group offsets
  u32*   CNTB = (u32*)(OFF + 18);             // NA*17 per-block counts

  int NA = B / 256;                           // 16   prep+cls blocks
  int NB = B / 8;                             // 512  rowstats blocks (32 rows)
  int NC = 1024;                              // recon blocks (512 per half)
  int N4 = B * H / 4;

  hipMemsetAsync(d_ws, 0, zeroBytes, stream);
  k_pre<<<NA + NB + NC, 256, 0, stream>>>(
      mask, y1, dom, l1, l2, l3, y2, y3, vsv, vst,
      cv, sv, ct, st, ir, io, trc, to,
      SA, GCU, U64, gid, sq, inv, bf, CNTB, B, N4, NA, NB);
  int NTR = B / 4;                            // transpose blocks (1024)
  k_mid<<<NA + NTR, 256, 0, stream>>>(CNTB, gid, sq, cv, sv, ct, st, inv,
                                      perm, sqp, OFF, bnT, B, NA);
  int NT = B / 64;
  int nmmd = 2 * (NT * (NT + 1) / 2);
  k_big<<<64 + nmmd, 256, 0, stream>>>(bf, sqp, perm, OFF, bnT, Mf32, GSP, B);
  k_hsic<<<dim3(8, 2), 256, 0, stream>>>(U64, Mf32, SA);
  k_final<<<1, 256, 0, stream>>>(SA, GCU, GSP, U64, (float*)d_out, B);
}